// Round 4
// baseline (405.035 us; speedup 1.0000x reference)
//
#include <hip/hip_runtime.h>
#include <cstdint>
#include <cstddef>

typedef unsigned short u16;
typedef __attribute__((ext_vector_type(8))) short short8;    // 8 bf16 (4 VGPRs) MFMA A/B frag (x32)
typedef __attribute__((ext_vector_type(4))) short short4v;   // 4 bf16 (2 VGPRs) MFMA A/B frag (x16)
typedef __attribute__((ext_vector_type(4))) float float4v;   // MFMA C/D frag
typedef __attribute__((ext_vector_type(4))) unsigned short ushort4v;
typedef __attribute__((ext_vector_type(2))) float float2v;

// ---------- helpers ----------
__device__ __forceinline__ u16 f2bf(float f) {
    union { float f; uint32_t u; } x; x.f = f;
    uint32_t r = x.u + 0x7fffu + ((x.u >> 16) & 1u);   // RTNE
    return (u16)(r >> 16);
}
// pack two fp32 -> two bf16 in one dword
__device__ __forceinline__ uint32_t pack_bf16x2(float lo, float hi) {
    union { float f; uint32_t u; } a, b; a.f = lo; b.f = hi;
    return __builtin_amdgcn_perm(b.u + 0x8000u, a.u + 0x8000u, 0x07060302u);
}
// async global->LDS, 16B per lane (HW: wave-uniform base + lane*16)
__device__ __forceinline__ void gl_lds16(const u16* g, u16* l) {
    __builtin_amdgcn_global_load_lds(
        (const __attribute__((address_space(1))) void*)g,
        (__attribute__((address_space(3))) void*)l, 16, 0, 0);
}

// ---------- 1. merged prep: cast x, rope table, weight transposes ----------
__global__ __launch_bounds__(256) void prep(const float4v* __restrict__ x,
                                            const float* __restrict__ Wq,
                                            const float* __restrict__ Wk,
                                            const float* __restrict__ Wv,
                                            const float* __restrict__ Wo,
                                            ushort4v* __restrict__ xb,
                                            u16* __restrict__ wqkv_t,
                                            u16* __restrict__ wo_t,
                                            float2v* __restrict__ tab) {
    __shared__ float lds[32][33];
    const int bid = blockIdx.x;
    const int tid = threadIdx.x;
    if (bid < 8192) {
        const int i = bid * 256 + tid;
        float4v v = x[i];
        ushort4v o;
        #pragma unroll
        for (int j = 0; j < 4; ++j) o[j] = f2bf(v[j]);
        xb[i] = o;
        return;
    }
    if (bid < 8448) {
        const int idx = (bid - 8192) * 256 + tid;   // 65536
        const int t = idx >> 5;
        const int i = idx & 31;
        const float invf = exp2f(-(float)i * (19.931568569324174f / 32.0f));
        float sv, cv;
        sincosf((float)t * invf, &sv, &cv);
        float2v o; o[0] = cv; o[1] = sv;
        tab[idx] = o;
        return;
    }
    const float* src;
    int Ns, n0, k0, scol0;
    u16* dst;
    if (bid < 14592) {
        const int id = bid - 8448;
        const int bx = id % 96, by = id / 96;
        n0 = bx * 32; k0 = by * 32;
        if (n0 < 2048)      { src = Wq; Ns = 2048; scol0 = n0; }
        else if (n0 < 2560) { src = Wk; Ns = 512;  scol0 = n0 - 2048; }
        else                { src = Wv; Ns = 512;  scol0 = n0 - 2560; }
        dst = wqkv_t;
    } else {
        const int id = bid - 14592;
        const int bx = id & 63, by = id >> 6;
        n0 = bx * 32; k0 = by * 32;
        src = Wo; Ns = 2048; scol0 = n0;
        dst = wo_t;
    }
    const int row = tid >> 3;            // k local
    const int c4  = (tid & 7) * 4;       // n local
    const float4v v = *(const float4v*)(src + (size_t)(k0 + row) * Ns + scol0 + c4);
    #pragma unroll
    for (int i = 0; i < 4; ++i) lds[row][c4 + i] = v[i];
    __syncthreads();
    const int nrow = tid >> 3;           // n local
    const int k4   = (tid & 7) * 4;      // k local
    ushort4v o;
    #pragma unroll
    for (int i = 0; i < 4; ++i) o[i] = f2bf(lds[k4 + i][nrow]);
    *(ushort4v*)(dst + (size_t)(n0 + nrow) * 2048 + k0 + k4) = o;
}

// ---------- 2. output-projection GEMM, m97 structure ----------
__global__ __launch_bounds__(256, 3) void gemm_bt(const u16* __restrict__ A,
                                                  const u16* __restrict__ Bt,
                                                  float* __restrict__ C,
                                                  int M, int N, int K) {
    __shared__ u16 lds_a[128 * 32];
    __shared__ u16 lds_b[128 * 32];
    const int tid  = threadIdx.x;
    const int wave = tid >> 6;
    const int lane = tid & 63;
    const int quad = lane >> 4;
    const int l15  = lane & 15;
    const long m0 = (long)blockIdx.x * 128;
    const long n0 = (long)blockIdx.y * 128;
    const int wm = (wave >> 1) * 64;
    const int wn = (wave & 1) * 64;
    const int s_row = tid >> 2;           // 0..63 (chunk c adds c*64)
    const int s_col = (tid & 3) * 8;      // 0,8,16,24 (u16 units)

    float4v acc[4][4];
    #pragma unroll
    for (int i = 0; i < 4; ++i)
        #pragma unroll
        for (int j = 0; j < 4; ++j)
            #pragma unroll
            for (int r = 0; r < 4; ++r) acc[i][j][r] = 0.0f;

    const u16* ga0 = A  + (m0 + s_row) * (long)K + s_col;
    const u16* ga1 = ga0 + 64 * (long)K;
    const u16* gb0 = Bt + (n0 + s_row) * (long)K + s_col;
    const u16* gb1 = gb0 + 64 * (long)K;
    u16* la = lds_a + tid * 8;            // byte offset tid*16: linear per wave
    u16* lb = lds_b + tid * 8;

    const int n_k = K >> 5;
    for (int it = 0; it < n_k; ++it) {
        const int k0 = it << 5;
        gl_lds16(ga0 + k0, la);
        gl_lds16(ga1 + k0, la + 2048);
        gl_lds16(gb0 + k0, lb);
        gl_lds16(gb1 + k0, lb + 2048);
        __syncthreads();                  // drains vmcnt(0): tile resident
        short8 af[4], bfr[4];
        #pragma unroll
        for (int mt = 0; mt < 4; ++mt)
            af[mt] = *(const short8*)(lds_a + (wm + mt * 16 + l15) * 32 + quad * 8);
        #pragma unroll
        for (int nt = 0; nt < 4; ++nt)
            bfr[nt] = *(const short8*)(lds_b + (wn + nt * 16 + l15) * 32 + quad * 8);
        #pragma unroll
        for (int mt = 0; mt < 4; ++mt)
            #pragma unroll
            for (int nt = 0; nt < 4; ++nt)
                acc[mt][nt] = __builtin_amdgcn_mfma_f32_16x16x32_bf16(af[mt], bfr[nt], acc[mt][nt], 0, 0, 0);
        __syncthreads();                  // all reads done before next overwrite
    }
    #pragma unroll
    for (int mt = 0; mt < 4; ++mt) {
        #pragma unroll
        for (int nt = 0; nt < 4; ++nt) {
            const long gr = m0 + wm + mt * 16 + quad * 4;
            const long gc = n0 + wn + nt * 16 + l15;
            #pragma unroll
            for (int r = 0; r < 4; ++r)
                C[(gr + r) * N + gc] = acc[mt][nt][r];
        }
    }
}

// ---------- 3. QKV GEMM, m97 structure, fused RMSNorm+RoPE+V-transpose ----------
// K output is stored with chunk-XOR swizzle (16B chunk index ^= key&7) and V
// output with key-permutation P(k) + chunk-XOR (^= d&7), so attn's linear
// global_load_lds staging lands a bank-conflict-reduced LDS layout directly.
__global__ __launch_bounds__(256, 3) void gemm_qkv(const u16* __restrict__ A,
                                                   const u16* __restrict__ Bt,
                                                   const float* __restrict__ qw,
                                                   const float* __restrict__ kw,
                                                   const float2v* __restrict__ tab,
                                                   u16* __restrict__ Qr,
                                                   u16* __restrict__ Kr,
                                                   u16* __restrict__ Vt) {
    const int K = 2048;
    __shared__ u16 lds_a[128 * 32];
    __shared__ u16 lds_b[128 * 32];
    const int tid  = threadIdx.x;
    const int wave = tid >> 6;
    const int lane = tid & 63;
    const int quad = lane >> 4;
    const int l15  = lane & 15;
    const long m0 = (long)blockIdx.x * 128;
    const long n0 = (long)blockIdx.y * 128;
    const int wm = (wave >> 1) * 64;
    const int wn = (wave & 1) * 64;
    const int s_row = tid >> 2;
    const int s_col = (tid & 3) * 8;

    float4v acc[4][4];
    #pragma unroll
    for (int i = 0; i < 4; ++i)
        #pragma unroll
        for (int j = 0; j < 4; ++j)
            #pragma unroll
            for (int r = 0; r < 4; ++r) acc[i][j][r] = 0.0f;

    const u16* ga0 = A  + (m0 + s_row) * (long)K + s_col;
    const u16* ga1 = ga0 + 64 * (long)K;
    const u16* gb0 = Bt + (n0 + s_row) * (long)K + s_col;
    const u16* gb1 = gb0 + 64 * (long)K;
    u16* la = lds_a + tid * 8;
    u16* lb = lds_b + tid * 8;

    const int n_k = K >> 5;   // 64
    for (int it = 0; it < n_k; ++it) {
        const int k0 = it << 5;
        gl_lds16(ga0 + k0, la);
        gl_lds16(ga1 + k0, la + 2048);
        gl_lds16(gb0 + k0, lb);
        gl_lds16(gb1 + k0, lb + 2048);
        __syncthreads();
        short8 af[4], bfr[4];
        #pragma unroll
        for (int mt = 0; mt < 4; ++mt)
            af[mt] = *(const short8*)(lds_a + (wm + mt * 16 + l15) * 32 + quad * 8);
        #pragma unroll
        for (int nt = 0; nt < 4; ++nt)
            bfr[nt] = *(const short8*)(lds_b + (wn + nt * 16 + l15) * 32 + quad * 8);
        #pragma unroll
        for (int mt = 0; mt < 4; ++mt)
            #pragma unroll
            for (int nt = 0; nt < 4; ++nt)
                acc[mt][nt] = __builtin_amdgcn_mfma_f32_16x16x32_bf16(af[mt], bfr[nt], acc[mt][nt], 0, 0, 0);
        __syncthreads();
    }

    const int col0 = (int)n0 + wn;          // 64-aligned; whole wave in one zone
    if (col0 < 2560) {
        // ---- Q or K head: RMSNorm + RoPE ----
        const bool isQ = (col0 < 2048);
        const float* lw = isQ ? qw : kw;
        float wreg[4];
        #pragma unroll
        for (int nt = 0; nt < 4; ++nt) wreg[nt] = lw[nt * 16 + l15];
        const float qs = isQ ? 0.18033688011112042f : 1.0f;   // 0.125*log2(e) for Q
        const int swm = isQ ? 0 : 7;        // K rows get chunk-XOR by key&7
        u16* dst = isQ ? (Qr + ((size_t)(col0 >> 6)) * 2048 * 64)
                       : (Kr + ((size_t)((col0 - 2048) >> 6)) * 2048 * 64);
        const size_t head_stride = isQ ? ((size_t)32 * 2048 * 64) : ((size_t)8 * 2048 * 64);
        #pragma unroll
        for (int mt = 0; mt < 4; ++mt) {
            const int gr0 = (int)m0 + wm + mt * 16 + quad * 4;
            const int b = gr0 >> 11, tt0 = gr0 & 2047;
            float rms[4];
            #pragma unroll
            for (int r = 0; r < 4; ++r) {
                float s = 0.0f;
                #pragma unroll
                for (int nt = 0; nt < 4; ++nt) s += acc[mt][nt][r] * acc[mt][nt][r];
                s += __shfl_xor(s, 1);
                s += __shfl_xor(s, 2);
                s += __shfl_xor(s, 4);
                s += __shfl_xor(s, 8);
                rms[r] = rsqrtf(s * (1.0f / 64.0f) + 1e-5f);
            }
            u16* rowp = dst + (size_t)b * head_stride + (size_t)tt0 * 64;
            #pragma unroll
            for (int nt = 0; nt < 2; ++nt) {
                const int i = nt * 16 + l15;
                #pragma unroll
                for (int r = 0; r < 4; ++r) {
                    const float2v cs = tab[(tt0 + r) * 32 + i];
                    const float v1 = acc[mt][nt][r]     * rms[r] * wreg[nt];
                    const float v2 = acc[mt][nt + 2][r] * rms[r] * wreg[nt + 2];
                    const float o1 = (v1 * cs[0] - v2 * cs[1]) * qs;
                    const float o2 = (v2 * cs[0] + v1 * cs[1]) * qs;
                    const int k7 = (tt0 + r) & swm;
                    const int i1 = (((i >> 3) ^ k7) << 3) | (i & 7);
                    const int i2 = ((((i + 32) >> 3) ^ k7) << 3) | (i & 7);
                    rowp[(size_t)r * 64 + i1] = f2bf(o1);
                    rowp[(size_t)r * 64 + i2] = f2bf(o2);
                }
            }
        }
    } else {
        // ---- V head: transpose to [head][d][t'], t' = swizzled P(t) ----
        const int kh = (col0 - 2560) >> 6;
        #pragma unroll
        for (int mt = 0; mt < 4; ++mt) {
            const int gr0 = (int)m0 + wm + mt * 16 + quad * 4;
            const int b = gr0 >> 11, tt0 = gr0 & 2047;
            const int tb = tt0 & ~127;
            const int tl = tt0 & 127;
            const int p0b = ((tl & 15) >> 2) * 32 + (tl >> 4) * 4;   // P(tl), &7 in {0,4}
            #pragma unroll
            for (int nt = 0; nt < 4; ++nt) {
                const int d = nt * 16 + l15;
                ushort4v o;
                #pragma unroll
                for (int r = 0; r < 4; ++r) o[r] = f2bf(acc[mt][nt][r]);
                const int col = tb + ((((p0b >> 3) ^ (d & 7)) << 3) | (p0b & 7));
                *(ushort4v*)(Vt + (((size_t)(b * 8 + kh)) * 64 + d) * 2048 + col) = o;
            }
        }
    }
}

// ---------- 4. flash attention: 8 waves x 2 q-frags (256-row q-tile) ----------
// Round-3's conflict-free layouts + gl_lds staging kept; wave count doubled to
// restore occupancy (2 blocks x 512 thr = 16 waves/CU = 4/SIMD). Each K/V LDS
// read still feeds 32 q-rows. Causal fold: qxA = 7-qxB over 256-row tiles;
// diagonal straddles the last TWO 128-key tiles of each phase.
#define SOFTMAX_PACK(S, m_i, l_i, O, pf)                                    \
    {                                                                       \
        float mx = S[0][0];                                                 \
        _Pragma("unroll")                                                   \
        for (int nt = 0; nt < 8; ++nt)                                      \
            _Pragma("unroll")                                               \
            for (int r = 0; r < 4; ++r) mx = fmaxf(mx, S[nt][r]);           \
        mx = fmaxf(mx, __shfl_xor(mx, 16));                                 \
        mx = fmaxf(mx, __shfl_xor(mx, 32));                                 \
        const float mnew = fmaxf(m_i, mx);                                  \
        const float alpha = __builtin_amdgcn_exp2f(m_i - mnew);             \
        m_i = mnew;                                                         \
        float rs = 0.0f;                                                    \
        _Pragma("unroll")                                                   \
        for (int nt = 0; nt < 8; ++nt)                                      \
            _Pragma("unroll")                                               \
            for (int r = 0; r < 4; ++r) {                                   \
                const float pv = __builtin_amdgcn_exp2f(S[nt][r] - mnew);   \
                S[nt][r] = pv;                                              \
                rs += pv;                                                   \
            }                                                               \
        rs += __shfl_xor(rs, 16);                                           \
        rs += __shfl_xor(rs, 32);                                           \
        l_i = l_i * alpha + rs;                                             \
        _Pragma("unroll")                                                   \
        for (int dt = 0; dt < 4; ++dt)                                      \
            _Pragma("unroll")                                               \
            for (int r = 0; r < 4; ++r) O[dt][r] *= alpha;                  \
        _Pragma("unroll")                                                   \
        for (int nt = 0; nt < 8; ++nt) {                                    \
            union { uint32_t u[2]; short4v s; } pu;                         \
            pu.u[0] = pack_bf16x2(S[nt][0], S[nt][1]);                      \
            pu.u[1] = pack_bf16x2(S[nt][2], S[nt][3]);                      \
            pf[nt] = pu.s;                                                  \
        }                                                                   \
    }

#define WRITE_O(O, l_i, qrow)                                               \
    {                                                                       \
        const float rl = 1.0f / l_i;                                        \
        _Pragma("unroll")                                                   \
        for (int dt = 0; dt < 4; ++dt) {                                    \
            ushort4v o;                                                     \
            _Pragma("unroll")                                               \
            for (int r = 0; r < 4; ++r) o[r] = f2bf(O[dt][r] * rl);         \
            *(ushort4v*)(Ob + ((size_t)(b * 2048 + (qrow))) * 2048 +        \
                         h * 64 + dt * 16 + quad * 4) = o;                  \
        }                                                                   \
    }

__global__ __launch_bounds__(512, 4) void attn_fwd(const u16* __restrict__ Qr,
                                                   const u16* __restrict__ Kr,
                                                   const u16* __restrict__ Vt,
                                                   u16* __restrict__ Ob) {
    __shared__ u16 lds_k[2][128 * 64];   // [key][swz 16B-chunk of d]
    __shared__ u16 lds_v[2][64 * 128];   // [d][swz 16B-chunk of P(key)]
    const int tid  = threadIdx.x;
    const int wave = tid >> 6;              // 0..7
    const int lane = tid & 63;
    const int quad = lane >> 4;
    const int l15  = lane & 15;
    const int sw7  = l15 & 7;
    const int qxB = blockIdx.y;             // 0..3
    const int qxA = 7 - qxB;                // 7..4
    const int bh = blockIdx.x;              // 0..63 (fast dim: head-sharing blocks on one XCD)
    const int b = bh >> 5, h = bh & 31;
    const int kh = h >> 2;
    const u16* Qh = Qr + ((size_t)(b * 32 + h))  * 2048 * 64;
    const u16* Kh = Kr + ((size_t)(b * 8 + kh))  * 2048 * 64;
    const u16* Vh = Vt + ((size_t)(b * 8 + kh))  * 64 * 2048;

    const int w32 = wave * 32;
    int qrow_c0 = qxA * 256 + w32 + l15;
    int qrow_c1 = qrow_c0 + 16;
    short8 qf[2][2];   // [frag][ks]
    #pragma unroll
    for (int ks = 0; ks < 2; ++ks) {
        qf[0][ks] = *(const short8*)(Qh + (size_t)qrow_c0 * 64 + ks * 32 + quad * 8);
        qf[1][ks] = *(const short8*)(Qh + (size_t)qrow_c1 * 64 + ks * 32 + quad * 8);
    }

    float m0v = -3e38f, l0v = 0.0f, m1v = -3e38f, l1v = 0.0f;
    float4v O0[4], O1[4];
    #pragma unroll
    for (int dt = 0; dt < 4; ++dt)
        #pragma unroll
        for (int r = 0; r < 4; ++r) { O0[dt][r] = 0.0f; O1[dt][r] = 0.0f; }

    // stage one 128-key tile (K 16KB + V 16KB) into buffer pb, key base k0
    const int vrow = tid >> 4;              // 0..31 (+ j*32)
    const int vchk = (tid & 15) * 8;        // u16 chunk offset within 128-key tile
    auto stage = [&](int pb, int k0) {
        #pragma unroll
        for (int j = 0; j < 2; ++j)
            gl_lds16(Kh + (size_t)k0 * 64 + (j * 512 + tid) * 8,
                     &lds_k[pb][(j * 512 + tid) * 8]);
        #pragma unroll
        for (int j = 0; j < 2; ++j)
            gl_lds16(Vh + (size_t)(j * 32 + vrow) * 2048 + k0 + vchk,
                     &lds_v[pb][(j * 512 + tid) * 8]);
    };
    stage(0, 0);
    __syncthreads();

    const int nA = 2 * qxA + 2;             // key tiles in phase A
    const int n_it = 18;                    // nA + nB = 2*(qxA+qxB)+4
    for (int i = 0; i < n_it; ++i) {
        const int p = i & 1;
        const int kt_cur = (i < nA) ? i : (i - nA);
        const int kt0 = kt_cur << 7;

        if (i + 1 < n_it) {
            const int ip1 = i + 1;
            const int ktn = (ip1 < nA) ? ip1 : (ip1 - nA);
            stage(1 - p, ktn << 7);
        }

        float4v S0[8], S1[8];
        #pragma unroll
        for (int nt = 0; nt < 8; ++nt)
            #pragma unroll
            for (int r = 0; r < 4; ++r) { S0[nt][r] = 0.0f; S1[nt][r] = 0.0f; }
        __builtin_amdgcn_s_setprio(1);
        #pragma unroll
        for (int ks = 0; ks < 2; ++ks) {
            #pragma unroll
            for (int nt = 0; nt < 8; ++nt) {
                short8 kf = *(const short8*)(lds_k[p] + (nt * 16 + l15) * 64 +
                                             (((ks * 4 + quad) ^ sw7) << 3));
                S0[nt] = __builtin_amdgcn_mfma_f32_16x16x32_bf16(kf, qf[0][ks], S0[nt], 0, 0, 0);
                S1[nt] = __builtin_amdgcn_mfma_f32_16x16x32_bf16(kf, qf[1][ks], S1[nt], 0, 0, 0);
            }
        }
        __builtin_amdgcn_s_setprio(0);

        // diagonal straddles the last two key tiles of each phase
        if ((i >= nA - 2 && i < nA) || (i >= n_it - 2)) {
            #pragma unroll
            for (int nt = 0; nt < 8; ++nt) {
                const int keyb = kt0 + nt * 16 + quad * 4;
                #pragma unroll
                for (int r = 0; r < 4; ++r) {
                    if (keyb + r > qrow_c0) S0[nt][r] = -3e38f;
                    if (keyb + r > qrow_c1) S1[nt][r] = -3e38f;
                }
            }
        }

        short4v pf0[8], pf1[8];
        SOFTMAX_PACK(S0, m0v, l0v, O0, pf0);
        SOFTMAX_PACK(S1, m1v, l1v, O1, pf1);

        __builtin_amdgcn_s_setprio(1);
        #pragma unroll
        for (int nt2 = 0; nt2 < 4; ++nt2) {
            #pragma unroll
            for (int dt = 0; dt < 4; ++dt) {
                short8 vv = *(const short8*)(lds_v[p] + (dt * 16 + l15) * 128 +
                                             (((quad * 4 + nt2) ^ sw7) << 3));
                short4v vlo = __builtin_shufflevector(vv, vv, 0, 1, 2, 3);
                short4v vhi = __builtin_shufflevector(vv, vv, 4, 5, 6, 7);
                O0[dt] = __builtin_amdgcn_mfma_f32_16x16x16bf16_1k(vlo, pf0[2 * nt2],     O0[dt], 0, 0, 0);
                O0[dt] = __builtin_amdgcn_mfma_f32_16x16x16bf16_1k(vhi, pf0[2 * nt2 + 1], O0[dt], 0, 0, 0);
                O1[dt] = __builtin_amdgcn_mfma_f32_16x16x16bf16_1k(vlo, pf1[2 * nt2],     O1[dt], 0, 0, 0);
                O1[dt] = __builtin_amdgcn_mfma_f32_16x16x16bf16_1k(vhi, pf1[2 * nt2 + 1], O1[dt], 0, 0, 0);
            }
        }
        __builtin_amdgcn_s_setprio(0);

        if (i == nA - 1) {
            WRITE_O(O0, l0v, qrow_c0);
            WRITE_O(O1, l1v, qrow_c1);
            m0v = -3e38f; l0v = 0.0f; m1v = -3e38f; l1v = 0.0f;
            #pragma unroll
            for (int dt = 0; dt < 4; ++dt)
                #pragma unroll
                for (int r = 0; r < 4; ++r) { O0[dt][r] = 0.0f; O1[dt][r] = 0.0f; }
            qrow_c0 = qxB * 256 + w32 + l15;
            qrow_c1 = qrow_c0 + 16;
            #pragma unroll
            for (int ks = 0; ks < 2; ++ks) {
                qf[0][ks] = *(const short8*)(Qh + (size_t)qrow_c0 * 64 + ks * 32 + quad * 8);
                qf[1][ks] = *(const short8*)(Qh + (size_t)qrow_c1 * 64 + ks * 32 + quad * 8);
            }
        }
        __syncthreads();
    }
    WRITE_O(O0, l0v, qrow_c0);
    WRITE_O(O1, l1v, qrow_c1);
}

// ---------- launcher ----------
extern "C" void kernel_launch(void* const* d_in, const int* in_sizes, int n_in,
                              void* d_out, int out_size, void* d_ws, size_t ws_size,
                              hipStream_t stream) {
    (void)in_sizes; (void)n_in; (void)out_size; (void)ws_size;
    const float* x  = (const float*)d_in[0];
    const float* Wq = (const float*)d_in[1];
    const float* Wk = (const float*)d_in[2];
    const float* Wv = (const float*)d_in[3];
    const float* Wo = (const float*)d_in[4];
    const float* qw = (const float*)d_in[5];
    const float* kw = (const float*)d_in[6];
    float* out = (float*)d_out;

    char* ws = (char*)d_ws;
    size_t off = 0;
    auto alloc = [&](size_t bytes) {
        char* p = ws + off;
        off += (bytes + 255) & ~(size_t)255;
        return p;
    };
    u16* xb     = (u16*)alloc((size_t)8388608 * 2);        // x bf16       16 MB
    u16* wqkv_t = (u16*)alloc((size_t)3072 * 2048 * 2);    // [n][k]       12 MB
    u16* wo_t   = (u16*)alloc((size_t)2048 * 2048 * 2);    //               8 MB
    u16* q_r    = (u16*)alloc((size_t)2 * 32 * 2048 * 64 * 2);  // 16 MB
    u16* k_r    = (u16*)alloc((size_t)2 * 8 * 2048 * 64 * 2);   //  4 MB (chunk-swizzled)
    u16* v_r    = (u16*)alloc((size_t)2 * 8 * 64 * 2048 * 2);   //  4 MB (d-major, P+XOR swz)
    float2v* rtab = (float2v*)alloc((size_t)2048 * 32 * 8);     // 512 KB
    u16* attnb  = xb;   // reuse: xb dead after gemm_qkv

    hipLaunchKernelGGL(prep, dim3(18688), dim3(256), 0, stream,
                       (const float4v*)x, Wq, Wk, Wv, Wo,
                       (ushort4v*)xb, wqkv_t, wo_t, rtab);
    hipLaunchKernelGGL(gemm_qkv, dim3(32, 24), dim3(256), 0, stream,
                       xb, wqkv_t, qw, kw, rtab, q_r, k_r, v_r);
    hipLaunchKernelGGL(attn_fwd, dim3(64, 4), dim3(512), 0, stream, q_r, k_r, v_r, attnb);
    hipLaunchKernelGGL(gemm_bt, dim3(32, 16), dim3(256), 0, stream,
                       attnb, wo_t, out, 4096, 2048, 2048);
}

// Round 5
// 291.373 us; speedup vs baseline: 1.3901x; 1.3901x over previous
//
#include <hip/hip_runtime.h>
#include <cstdint>
#include <cstddef>

typedef unsigned short u16;
typedef __attribute__((ext_vector_type(8))) short short8;    // 8 bf16 (4 VGPRs) MFMA A/B frag (x32)
typedef __attribute__((ext_vector_type(4))) short short4v;   // 4 bf16 (2 VGPRs) MFMA A/B frag (x16)
typedef __attribute__((ext_vector_type(4))) float float4v;   // MFMA C/D frag
typedef __attribute__((ext_vector_type(4))) unsigned short ushort4v;
typedef __attribute__((ext_vector_type(2))) float float2v;

// ---------- helpers ----------
__device__ __forceinline__ u16 f2bf(float f) {
    union { float f; uint32_t u; } x; x.f = f;
    uint32_t r = x.u + 0x7fffu + ((x.u >> 16) & 1u);   // RTNE
    return (u16)(r >> 16);
}
// pack two fp32 -> two bf16 in one dword
__device__ __forceinline__ uint32_t pack_bf16x2(float lo, float hi) {
    union { float f; uint32_t u; } a, b; a.f = lo; b.f = hi;
    return __builtin_amdgcn_perm(b.u + 0x8000u, a.u + 0x8000u, 0x07060302u);
}
// async global->LDS, 16B per lane (HW: wave-uniform base + lane*16)
__device__ __forceinline__ void gl_lds16(const u16* g, u16* l) {
    __builtin_amdgcn_global_load_lds(
        (const __attribute__((address_space(1))) void*)g,
        (__attribute__((address_space(3))) void*)l, 16, 0, 0);
}

// ---------- 1. merged prep: cast x, rope table, weight transposes ----------
__global__ __launch_bounds__(256) void prep(const float4v* __restrict__ x,
                                            const float* __restrict__ Wq,
                                            const float* __restrict__ Wk,
                                            const float* __restrict__ Wv,
                                            const float* __restrict__ Wo,
                                            ushort4v* __restrict__ xb,
                                            u16* __restrict__ wqkv_t,
                                            u16* __restrict__ wo_t,
                                            float2v* __restrict__ tab) {
    __shared__ float lds[32][33];
    const int bid = blockIdx.x;
    const int tid = threadIdx.x;
    if (bid < 8192) {
        const int i = bid * 256 + tid;
        float4v v = x[i];
        ushort4v o;
        #pragma unroll
        for (int j = 0; j < 4; ++j) o[j] = f2bf(v[j]);
        xb[i] = o;
        return;
    }
    if (bid < 8448) {
        const int idx = (bid - 8192) * 256 + tid;   // 65536
        const int t = idx >> 5;
        const int i = idx & 31;
        const float invf = exp2f(-(float)i * (19.931568569324174f / 32.0f));
        float sv, cv;
        sincosf((float)t * invf, &sv, &cv);
        float2v o; o[0] = cv; o[1] = sv;
        tab[idx] = o;
        return;
    }
    const float* src;
    int Ns, n0, k0, scol0;
    u16* dst;
    if (bid < 14592) {
        const int id = bid - 8448;
        const int bx = id % 96, by = id / 96;
        n0 = bx * 32; k0 = by * 32;
        if (n0 < 2048)      { src = Wq; Ns = 2048; scol0 = n0; }
        else if (n0 < 2560) { src = Wk; Ns = 512;  scol0 = n0 - 2048; }
        else                { src = Wv; Ns = 512;  scol0 = n0 - 2560; }
        dst = wqkv_t;
    } else {
        const int id = bid - 14592;
        const int bx = id & 63, by = id >> 6;
        n0 = bx * 32; k0 = by * 32;
        src = Wo; Ns = 2048; scol0 = n0;
        dst = wo_t;
    }
    const int row = tid >> 3;            // k local
    const int c4  = (tid & 7) * 4;       // n local
    const float4v v = *(const float4v*)(src + (size_t)(k0 + row) * Ns + scol0 + c4);
    #pragma unroll
    for (int i = 0; i < 4; ++i) lds[row][c4 + i] = v[i];
    __syncthreads();
    const int nrow = tid >> 3;           // n local
    const int k4   = (tid & 7) * 4;      // k local
    ushort4v o;
    #pragma unroll
    for (int i = 0; i < 4; ++i) o[i] = f2bf(lds[k4 + i][nrow]);
    *(ushort4v*)(dst + (size_t)(n0 + nrow) * 2048 + k0 + k4) = o;
}

// ---------- 2. output-projection GEMM, m97 structure ----------
__global__ __launch_bounds__(256, 3) void gemm_bt(const u16* __restrict__ A,
                                                  const u16* __restrict__ Bt,
                                                  float* __restrict__ C,
                                                  int M, int N, int K) {
    __shared__ u16 lds_a[128 * 32];
    __shared__ u16 lds_b[128 * 32];
    const int tid  = threadIdx.x;
    const int wave = tid >> 6;
    const int lane = tid & 63;
    const int quad = lane >> 4;
    const int l15  = lane & 15;
    const long m0 = (long)blockIdx.x * 128;
    const long n0 = (long)blockIdx.y * 128;
    const int wm = (wave >> 1) * 64;
    const int wn = (wave & 1) * 64;
    const int s_row = tid >> 2;           // 0..63 (chunk c adds c*64)
    const int s_col = (tid & 3) * 8;      // 0,8,16,24 (u16 units)

    float4v acc[4][4];
    #pragma unroll
    for (int i = 0; i < 4; ++i)
        #pragma unroll
        for (int j = 0; j < 4; ++j)
            #pragma unroll
            for (int r = 0; r < 4; ++r) acc[i][j][r] = 0.0f;

    const u16* ga0 = A  + (m0 + s_row) * (long)K + s_col;
    const u16* ga1 = ga0 + 64 * (long)K;
    const u16* gb0 = Bt + (n0 + s_row) * (long)K + s_col;
    const u16* gb1 = gb0 + 64 * (long)K;
    u16* la = lds_a + tid * 8;            // byte offset tid*16: linear per wave
    u16* lb = lds_b + tid * 8;

    const int n_k = K >> 5;
    for (int it = 0; it < n_k; ++it) {
        const int k0 = it << 5;
        gl_lds16(ga0 + k0, la);
        gl_lds16(ga1 + k0, la + 2048);
        gl_lds16(gb0 + k0, lb);
        gl_lds16(gb1 + k0, lb + 2048);
        __syncthreads();                  // drains vmcnt(0): tile resident
        short8 af[4], bfr[4];
        #pragma unroll
        for (int mt = 0; mt < 4; ++mt)
            af[mt] = *(const short8*)(lds_a + (wm + mt * 16 + l15) * 32 + quad * 8);
        #pragma unroll
        for (int nt = 0; nt < 4; ++nt)
            bfr[nt] = *(const short8*)(lds_b + (wn + nt * 16 + l15) * 32 + quad * 8);
        #pragma unroll
        for (int mt = 0; mt < 4; ++mt)
            #pragma unroll
            for (int nt = 0; nt < 4; ++nt)
                acc[mt][nt] = __builtin_amdgcn_mfma_f32_16x16x32_bf16(af[mt], bfr[nt], acc[mt][nt], 0, 0, 0);
        __syncthreads();                  // all reads done before next overwrite
    }
    #pragma unroll
    for (int mt = 0; mt < 4; ++mt) {
        #pragma unroll
        for (int nt = 0; nt < 4; ++nt) {
            const long gr = m0 + wm + mt * 16 + quad * 4;
            const long gc = n0 + wn + nt * 16 + l15;
            #pragma unroll
            for (int r = 0; r < 4; ++r)
                C[(gr + r) * N + gc] = acc[mt][nt][r];
        }
    }
}

// ---------- 3. QKV GEMM, m97 structure, fused RMSNorm+RoPE+V-transpose ----------
// K output is stored with chunk-XOR swizzle (16B chunk index ^= key&7) and V
// output with key-permutation P(k) + chunk-XOR (^= d&7), so attn's linear
// global_load_lds staging lands a bank-conflict-reduced LDS layout directly.
__global__ __launch_bounds__(256, 3) void gemm_qkv(const u16* __restrict__ A,
                                                   const u16* __restrict__ Bt,
                                                   const float* __restrict__ qw,
                                                   const float* __restrict__ kw,
                                                   const float2v* __restrict__ tab,
                                                   u16* __restrict__ Qr,
                                                   u16* __restrict__ Kr,
                                                   u16* __restrict__ Vt) {
    const int K = 2048;
    __shared__ u16 lds_a[128 * 32];
    __shared__ u16 lds_b[128 * 32];
    const int tid  = threadIdx.x;
    const int wave = tid >> 6;
    const int lane = tid & 63;
    const int quad = lane >> 4;
    const int l15  = lane & 15;
    const long m0 = (long)blockIdx.x * 128;
    const long n0 = (long)blockIdx.y * 128;
    const int wm = (wave >> 1) * 64;
    const int wn = (wave & 1) * 64;
    const int s_row = tid >> 2;
    const int s_col = (tid & 3) * 8;

    float4v acc[4][4];
    #pragma unroll
    for (int i = 0; i < 4; ++i)
        #pragma unroll
        for (int j = 0; j < 4; ++j)
            #pragma unroll
            for (int r = 0; r < 4; ++r) acc[i][j][r] = 0.0f;

    const u16* ga0 = A  + (m0 + s_row) * (long)K + s_col;
    const u16* ga1 = ga0 + 64 * (long)K;
    const u16* gb0 = Bt + (n0 + s_row) * (long)K + s_col;
    const u16* gb1 = gb0 + 64 * (long)K;
    u16* la = lds_a + tid * 8;
    u16* lb = lds_b + tid * 8;

    const int n_k = K >> 5;   // 64
    for (int it = 0; it < n_k; ++it) {
        const int k0 = it << 5;
        gl_lds16(ga0 + k0, la);
        gl_lds16(ga1 + k0, la + 2048);
        gl_lds16(gb0 + k0, lb);
        gl_lds16(gb1 + k0, lb + 2048);
        __syncthreads();
        short8 af[4], bfr[4];
        #pragma unroll
        for (int mt = 0; mt < 4; ++mt)
            af[mt] = *(const short8*)(lds_a + (wm + mt * 16 + l15) * 32 + quad * 8);
        #pragma unroll
        for (int nt = 0; nt < 4; ++nt)
            bfr[nt] = *(const short8*)(lds_b + (wn + nt * 16 + l15) * 32 + quad * 8);
        #pragma unroll
        for (int mt = 0; mt < 4; ++mt)
            #pragma unroll
            for (int nt = 0; nt < 4; ++nt)
                acc[mt][nt] = __builtin_amdgcn_mfma_f32_16x16x32_bf16(af[mt], bfr[nt], acc[mt][nt], 0, 0, 0);
        __syncthreads();
    }

    const int col0 = (int)n0 + wn;          // 64-aligned; whole wave in one zone
    if (col0 < 2560) {
        // ---- Q or K head: RMSNorm + RoPE ----
        const bool isQ = (col0 < 2048);
        const float* lw = isQ ? qw : kw;
        float wreg[4];
        #pragma unroll
        for (int nt = 0; nt < 4; ++nt) wreg[nt] = lw[nt * 16 + l15];
        const float qs = isQ ? 0.18033688011112042f : 1.0f;   // 0.125*log2(e) for Q
        const int swm = isQ ? 0 : 7;        // K rows get chunk-XOR by key&7
        u16* dst = isQ ? (Qr + ((size_t)(col0 >> 6)) * 2048 * 64)
                       : (Kr + ((size_t)((col0 - 2048) >> 6)) * 2048 * 64);
        const size_t head_stride = isQ ? ((size_t)32 * 2048 * 64) : ((size_t)8 * 2048 * 64);
        #pragma unroll
        for (int mt = 0; mt < 4; ++mt) {
            const int gr0 = (int)m0 + wm + mt * 16 + quad * 4;
            const int b = gr0 >> 11, tt0 = gr0 & 2047;
            float rms[4];
            #pragma unroll
            for (int r = 0; r < 4; ++r) {
                float s = 0.0f;
                #pragma unroll
                for (int nt = 0; nt < 4; ++nt) s += acc[mt][nt][r] * acc[mt][nt][r];
                s += __shfl_xor(s, 1);
                s += __shfl_xor(s, 2);
                s += __shfl_xor(s, 4);
                s += __shfl_xor(s, 8);
                rms[r] = rsqrtf(s * (1.0f / 64.0f) + 1e-5f);
            }
            u16* rowp = dst + (size_t)b * head_stride + (size_t)tt0 * 64;
            #pragma unroll
            for (int nt = 0; nt < 2; ++nt) {
                const int i = nt * 16 + l15;
                #pragma unroll
                for (int r = 0; r < 4; ++r) {
                    const float2v cs = tab[(tt0 + r) * 32 + i];
                    const float v1 = acc[mt][nt][r]     * rms[r] * wreg[nt];
                    const float v2 = acc[mt][nt + 2][r] * rms[r] * wreg[nt + 2];
                    const float o1 = (v1 * cs[0] - v2 * cs[1]) * qs;
                    const float o2 = (v2 * cs[0] + v1 * cs[1]) * qs;
                    const int k7 = (tt0 + r) & swm;
                    const int i1 = (((i >> 3) ^ k7) << 3) | (i & 7);
                    const int i2 = ((((i + 32) >> 3) ^ k7) << 3) | (i & 7);
                    rowp[(size_t)r * 64 + i1] = f2bf(o1);
                    rowp[(size_t)r * 64 + i2] = f2bf(o2);
                }
            }
        }
    } else {
        // ---- V head: transpose to [head][d][t'], t' = swizzled P(t) ----
        const int kh = (col0 - 2560) >> 6;
        #pragma unroll
        for (int mt = 0; mt < 4; ++mt) {
            const int gr0 = (int)m0 + wm + mt * 16 + quad * 4;
            const int b = gr0 >> 11, tt0 = gr0 & 2047;
            const int tb = tt0 & ~127;
            const int tl = tt0 & 127;
            const int p0b = ((tl & 15) >> 2) * 32 + (tl >> 4) * 4;   // P(tl), &7 in {0,4}
            #pragma unroll
            for (int nt = 0; nt < 4; ++nt) {
                const int d = nt * 16 + l15;
                ushort4v o;
                #pragma unroll
                for (int r = 0; r < 4; ++r) o[r] = f2bf(acc[mt][nt][r]);
                const int col = tb + ((((p0b >> 3) ^ (d & 7)) << 3) | (p0b & 7));
                *(ushort4v*)(Vt + (((size_t)(b * 8 + kh)) * 64 + d) * 2048 + col) = o;
            }
        }
    }
}

// ---------- 4. flash attention: 8 waves x 2 q-frags (256-row q-tile) ----------
// launch_bounds (512,2): round 4's (512,4) capped VGPR at 64 -> per-thread
// S/O/pf state spilled to scratch (WRITE_SIZE 335MB, 2.5x slowdown). Natural
// footprint ~96-110 regs (round-3 evidence); cap 256 lets it fit, occupancy
// stays LDS-limited at 2 blocks/CU = 4 waves/SIMD.
#define SOFTMAX_PACK(S, m_i, l_i, O, pf)                                    \
    {                                                                       \
        float mx = S[0][0];                                                 \
        _Pragma("unroll")                                                   \
        for (int nt = 0; nt < 8; ++nt)                                      \
            _Pragma("unroll")                                               \
            for (int r = 0; r < 4; ++r) mx = fmaxf(mx, S[nt][r]);           \
        mx = fmaxf(mx, __shfl_xor(mx, 16));                                 \
        mx = fmaxf(mx, __shfl_xor(mx, 32));                                 \
        const float mnew = fmaxf(m_i, mx);                                  \
        const float alpha = __builtin_amdgcn_exp2f(m_i - mnew);             \
        m_i = mnew;                                                         \
        float rs = 0.0f;                                                    \
        _Pragma("unroll")                                                   \
        for (int nt = 0; nt < 8; ++nt)                                      \
            _Pragma("unroll")                                               \
            for (int r = 0; r < 4; ++r) {                                   \
                const float pv = __builtin_amdgcn_exp2f(S[nt][r] - mnew);   \
                S[nt][r] = pv;                                              \
                rs += pv;                                                   \
            }                                                               \
        rs += __shfl_xor(rs, 16);                                           \
        rs += __shfl_xor(rs, 32);                                           \
        l_i = l_i * alpha + rs;                                             \
        _Pragma("unroll")                                                   \
        for (int dt = 0; dt < 4; ++dt)                                      \
            _Pragma("unroll")                                               \
            for (int r = 0; r < 4; ++r) O[dt][r] *= alpha;                  \
        _Pragma("unroll")                                                   \
        for (int nt = 0; nt < 8; ++nt) {                                    \
            union { uint32_t u[2]; short4v s; } pu;                         \
            pu.u[0] = pack_bf16x2(S[nt][0], S[nt][1]);                      \
            pu.u[1] = pack_bf16x2(S[nt][2], S[nt][3]);                      \
            pf[nt] = pu.s;                                                  \
        }                                                                   \
    }

#define WRITE_O(O, l_i, qrow)                                               \
    {                                                                       \
        const float rl = 1.0f / l_i;                                        \
        _Pragma("unroll")                                                   \
        for (int dt = 0; dt < 4; ++dt) {                                    \
            ushort4v o;                                                     \
            _Pragma("unroll")                                               \
            for (int r = 0; r < 4; ++r) o[r] = f2bf(O[dt][r] * rl);         \
            *(ushort4v*)(Ob + ((size_t)(b * 2048 + (qrow))) * 2048 +        \
                         h * 64 + dt * 16 + quad * 4) = o;                  \
        }                                                                   \
    }

__global__ __launch_bounds__(512, 2) void attn_fwd(const u16* __restrict__ Qr,
                                                   const u16* __restrict__ Kr,
                                                   const u16* __restrict__ Vt,
                                                   u16* __restrict__ Ob) {
    __shared__ u16 lds_k[2][128 * 64];   // [key][swz 16B-chunk of d]
    __shared__ u16 lds_v[2][64 * 128];   // [d][swz 16B-chunk of P(key)]
    const int tid  = threadIdx.x;
    const int wave = tid >> 6;              // 0..7
    const int lane = tid & 63;
    const int quad = lane >> 4;
    const int l15  = lane & 15;
    const int sw7  = l15 & 7;
    const int qxB = blockIdx.y;             // 0..3
    const int qxA = 7 - qxB;                // 7..4
    const int bh = blockIdx.x;              // 0..63 (fast dim: head-sharing blocks on one XCD)
    const int b = bh >> 5, h = bh & 31;
    const int kh = h >> 2;
    const u16* Qh = Qr + ((size_t)(b * 32 + h))  * 2048 * 64;
    const u16* Kh = Kr + ((size_t)(b * 8 + kh))  * 2048 * 64;
    const u16* Vh = Vt + ((size_t)(b * 8 + kh))  * 64 * 2048;

    const int w32 = wave * 32;
    int qrow_c0 = qxA * 256 + w32 + l15;
    int qrow_c1 = qrow_c0 + 16;
    short8 qf[2][2];   // [frag][ks]
    #pragma unroll
    for (int ks = 0; ks < 2; ++ks) {
        qf[0][ks] = *(const short8*)(Qh + (size_t)qrow_c0 * 64 + ks * 32 + quad * 8);
        qf[1][ks] = *(const short8*)(Qh + (size_t)qrow_c1 * 64 + ks * 32 + quad * 8);
    }

    float m0v = -3e38f, l0v = 0.0f, m1v = -3e38f, l1v = 0.0f;
    float4v O0[4], O1[4];
    #pragma unroll
    for (int dt = 0; dt < 4; ++dt)
        #pragma unroll
        for (int r = 0; r < 4; ++r) { O0[dt][r] = 0.0f; O1[dt][r] = 0.0f; }

    // stage one 128-key tile (K 16KB + V 16KB) into buffer pb, key base k0
    const int vrow = tid >> 4;              // 0..31 (+ j*32)
    const int vchk = (tid & 15) * 8;        // u16 chunk offset within 128-key tile
    auto stage = [&](int pb, int k0) {
        #pragma unroll
        for (int j = 0; j < 2; ++j)
            gl_lds16(Kh + (size_t)k0 * 64 + (j * 512 + tid) * 8,
                     &lds_k[pb][(j * 512 + tid) * 8]);
        #pragma unroll
        for (int j = 0; j < 2; ++j)
            gl_lds16(Vh + (size_t)(j * 32 + vrow) * 2048 + k0 + vchk,
                     &lds_v[pb][(j * 512 + tid) * 8]);
    };
    stage(0, 0);
    __syncthreads();

    const int nA = 2 * qxA + 2;             // key tiles in phase A
    const int n_it = 18;                    // nA + nB = 2*(qxA+qxB)+4
    for (int i = 0; i < n_it; ++i) {
        const int p = i & 1;
        const int kt_cur = (i < nA) ? i : (i - nA);
        const int kt0 = kt_cur << 7;

        if (i + 1 < n_it) {
            const int ip1 = i + 1;
            const int ktn = (ip1 < nA) ? ip1 : (ip1 - nA);
            stage(1 - p, ktn << 7);
        }

        float4v S0[8], S1[8];
        #pragma unroll
        for (int nt = 0; nt < 8; ++nt)
            #pragma unroll
            for (int r = 0; r < 4; ++r) { S0[nt][r] = 0.0f; S1[nt][r] = 0.0f; }
        __builtin_amdgcn_s_setprio(1);
        #pragma unroll
        for (int ks = 0; ks < 2; ++ks) {
            #pragma unroll
            for (int nt = 0; nt < 8; ++nt) {
                short8 kf = *(const short8*)(lds_k[p] + (nt * 16 + l15) * 64 +
                                             (((ks * 4 + quad) ^ sw7) << 3));
                S0[nt] = __builtin_amdgcn_mfma_f32_16x16x32_bf16(kf, qf[0][ks], S0[nt], 0, 0, 0);
                S1[nt] = __builtin_amdgcn_mfma_f32_16x16x32_bf16(kf, qf[1][ks], S1[nt], 0, 0, 0);
            }
        }
        __builtin_amdgcn_s_setprio(0);

        // diagonal straddles the last two key tiles of each phase
        if ((i >= nA - 2 && i < nA) || (i >= n_it - 2)) {
            #pragma unroll
            for (int nt = 0; nt < 8; ++nt) {
                const int keyb = kt0 + nt * 16 + quad * 4;
                #pragma unroll
                for (int r = 0; r < 4; ++r) {
                    if (keyb + r > qrow_c0) S0[nt][r] = -3e38f;
                    if (keyb + r > qrow_c1) S1[nt][r] = -3e38f;
                }
            }
        }

        short4v pf0[8], pf1[8];
        SOFTMAX_PACK(S0, m0v, l0v, O0, pf0);
        SOFTMAX_PACK(S1, m1v, l1v, O1, pf1);

        __builtin_amdgcn_s_setprio(1);
        #pragma unroll
        for (int nt2 = 0; nt2 < 4; ++nt2) {
            #pragma unroll
            for (int dt = 0; dt < 4; ++dt) {
                short8 vv = *(const short8*)(lds_v[p] + (dt * 16 + l15) * 128 +
                                             (((quad * 4 + nt2) ^ sw7) << 3));
                short4v vlo = __builtin_shufflevector(vv, vv, 0, 1, 2, 3);
                short4v vhi = __builtin_shufflevector(vv, vv, 4, 5, 6, 7);
                O0[dt] = __builtin_amdgcn_mfma_f32_16x16x16bf16_1k(vlo, pf0[2 * nt2],     O0[dt], 0, 0, 0);
                O0[dt] = __builtin_amdgcn_mfma_f32_16x16x16bf16_1k(vhi, pf0[2 * nt2 + 1], O0[dt], 0, 0, 0);
                O1[dt] = __builtin_amdgcn_mfma_f32_16x16x16bf16_1k(vlo, pf1[2 * nt2],     O1[dt], 0, 0, 0);
                O1[dt] = __builtin_amdgcn_mfma_f32_16x16x16bf16_1k(vhi, pf1[2 * nt2 + 1], O1[dt], 0, 0, 0);
            }
        }
        __builtin_amdgcn_s_setprio(0);

        if (i == nA - 1) {
            WRITE_O(O0, l0v, qrow_c0);
            WRITE_O(O1, l1v, qrow_c1);
            m0v = -3e38f; l0v = 0.0f; m1v = -3e38f; l1v = 0.0f;
            #pragma unroll
            for (int dt = 0; dt < 4; ++dt)
                #pragma unroll
                for (int r = 0; r < 4; ++r) { O0[dt][r] = 0.0f; O1[dt][r] = 0.0f; }
            qrow_c0 = qxB * 256 + w32 + l15;
            qrow_c1 = qrow_c0 + 16;
            #pragma unroll
            for (int ks = 0; ks < 2; ++ks) {
                qf[0][ks] = *(const short8*)(Qh + (size_t)qrow_c0 * 64 + ks * 32 + quad * 8);
                qf[1][ks] = *(const short8*)(Qh + (size_t)qrow_c1 * 64 + ks * 32 + quad * 8);
            }
        }
        __syncthreads();
    }
    WRITE_O(O0, l0v, qrow_c0);
    WRITE_O(O1, l1v, qrow_c1);
}

// ---------- launcher ----------
extern "C" void kernel_launch(void* const* d_in, const int* in_sizes, int n_in,
                              void* d_out, int out_size, void* d_ws, size_t ws_size,
                              hipStream_t stream) {
    (void)in_sizes; (void)n_in; (void)out_size; (void)ws_size;
    const float* x  = (const float*)d_in[0];
    const float* Wq = (const float*)d_in[1];
    const float* Wk = (const float*)d_in[2];
    const float* Wv = (const float*)d_in[3];
    const float* Wo = (const float*)d_in[4];
    const float* qw = (const float*)d_in[5];
    const float* kw = (const float*)d_in[6];
    float* out = (float*)d_out;

    char* ws = (char*)d_ws;
    size_t off = 0;
    auto alloc = [&](size_t bytes) {
        char* p = ws + off;
        off += (bytes + 255) & ~(size_t)255;
        return p;
    };
    u16* xb     = (u16*)alloc((size_t)8388608 * 2);        // x bf16       16 MB
    u16* wqkv_t = (u16*)alloc((size_t)3072 * 2048 * 2);    // [n][k]       12 MB
    u16* wo_t   = (u16*)alloc((size_t)2048 * 2048 * 2);    //               8 MB
    u16* q_r    = (u16*)alloc((size_t)2 * 32 * 2048 * 64 * 2);  // 16 MB
    u16* k_r    = (u16*)alloc((size_t)2 * 8 * 2048 * 64 * 2);   //  4 MB (chunk-swizzled)
    u16* v_r    = (u16*)alloc((size_t)2 * 8 * 64 * 2048 * 2);   //  4 MB (d-major, P+XOR swz)
    float2v* rtab = (float2v*)alloc((size_t)2048 * 32 * 8);     // 512 KB
    u16* attnb  = xb;   // reuse: xb dead after gemm_qkv

    hipLaunchKernelGGL(prep, dim3(18688), dim3(256), 0, stream,
                       (const float4v*)x, Wq, Wk, Wv, Wo,
                       (ushort4v*)xb, wqkv_t, wo_t, rtab);
    hipLaunchKernelGGL(gemm_qkv, dim3(32, 24), dim3(256), 0, stream,
                       xb, wqkv_t, qw, kw, rtab, q_r, k_r, v_r);
    hipLaunchKernelGGL(attn_fwd, dim3(64, 4), dim3(512), 0, stream, q_r, k_r, v_r, attnb);
    hipLaunchKernelGGL(gemm_bt, dim3(32, 16), dim3(256), 0, stream,
                       attnb, wo_t, out, 4096, 2048, 2048);
}

// Round 7
// 288.095 us; speedup vs baseline: 1.4059x; 1.0114x over previous
//
#include <hip/hip_runtime.h>
#include <cstdint>
#include <cstddef>

typedef unsigned short u16;
typedef __attribute__((ext_vector_type(8))) short short8;    // 8 bf16 (4 VGPRs) MFMA A/B frag (x32)
typedef __attribute__((ext_vector_type(4))) short short4v;   // 4 bf16 (2 VGPRs) MFMA A/B frag (x16)
typedef __attribute__((ext_vector_type(4))) float float4v;   // MFMA C/D frag
typedef __attribute__((ext_vector_type(4))) unsigned short ushort4v;
typedef __attribute__((ext_vector_type(2))) float float2v;

// ---------- helpers ----------
__device__ __forceinline__ u16 f2bf(float f) {
    union { float f; uint32_t u; } x; x.f = f;
    uint32_t r = x.u + 0x7fffu + ((x.u >> 16) & 1u);   // RTNE
    return (u16)(r >> 16);
}
// pack two fp32 -> two bf16 in one dword
__device__ __forceinline__ uint32_t pack_bf16x2(float lo, float hi) {
    union { float f; uint32_t u; } a, b; a.f = lo; b.f = hi;
    return __builtin_amdgcn_perm(b.u + 0x8000u, a.u + 0x8000u, 0x07060302u);
}
// async global->LDS, 16B per lane (HW: wave-uniform base + lane*16)
__device__ __forceinline__ void gl_lds16(const u16* g, u16* l) {
    __builtin_amdgcn_global_load_lds(
        (const __attribute__((address_space(1))) void*)g,
        (__attribute__((address_space(3))) void*)l, 16, 0, 0);
}

// ---------- 1. merged prep: cast x, rope table, weight transposes ----------
__global__ __launch_bounds__(256) void prep(const float4v* __restrict__ x,
                                            const float* __restrict__ Wq,
                                            const float* __restrict__ Wk,
                                            const float* __restrict__ Wv,
                                            const float* __restrict__ Wo,
                                            ushort4v* __restrict__ xb,
                                            u16* __restrict__ wqkv_t,
                                            u16* __restrict__ wo_t,
                                            float2v* __restrict__ tab) {
    __shared__ float lds[32][33];
    const int bid = blockIdx.x;
    const int tid = threadIdx.x;
    if (bid < 8192) {
        const int i = bid * 256 + tid;
        float4v v = x[i];
        ushort4v o;
        #pragma unroll
        for (int j = 0; j < 4; ++j) o[j] = f2bf(v[j]);
        xb[i] = o;
        return;
    }
    if (bid < 8448) {
        const int idx = (bid - 8192) * 256 + tid;   // 65536
        const int t = idx >> 5;
        const int i = idx & 31;
        const float invf = exp2f(-(float)i * (19.931568569324174f / 32.0f));
        float sv, cv;
        sincosf((float)t * invf, &sv, &cv);
        float2v o; o[0] = cv; o[1] = sv;
        tab[idx] = o;
        return;
    }
    const float* src;
    int Ns, n0, k0, scol0;
    u16* dst;
    if (bid < 14592) {
        const int id = bid - 8448;
        const int bx = id % 96, by = id / 96;
        n0 = bx * 32; k0 = by * 32;
        if (n0 < 2048)      { src = Wq; Ns = 2048; scol0 = n0; }
        else if (n0 < 2560) { src = Wk; Ns = 512;  scol0 = n0 - 2048; }
        else                { src = Wv; Ns = 512;  scol0 = n0 - 2560; }
        dst = wqkv_t;
    } else {
        const int id = bid - 14592;
        const int bx = id & 63, by = id >> 6;
        n0 = bx * 32; k0 = by * 32;
        src = Wo; Ns = 2048; scol0 = n0;
        dst = wo_t;
    }
    const int row = tid >> 3;            // k local
    const int c4  = (tid & 7) * 4;       // n local
    const float4v v = *(const float4v*)(src + (size_t)(k0 + row) * Ns + scol0 + c4);
    #pragma unroll
    for (int i = 0; i < 4; ++i) lds[row][c4 + i] = v[i];
    __syncthreads();
    const int nrow = tid >> 3;           // n local
    const int k4   = (tid & 7) * 4;      // k local
    ushort4v o;
    #pragma unroll
    for (int i = 0; i < 4; ++i) o[i] = f2bf(lds[k4 + i][nrow]);
    *(ushort4v*)(dst + (size_t)(n0 + nrow) * 2048 + k0 + k4) = o;
}

// ---------- 2. output-projection GEMM, m97 structure ----------
__global__ __launch_bounds__(256, 3) void gemm_bt(const u16* __restrict__ A,
                                                  const u16* __restrict__ Bt,
                                                  float* __restrict__ C,
                                                  int M, int N, int K) {
    __shared__ u16 lds_a[128 * 32];
    __shared__ u16 lds_b[128 * 32];
    const int tid  = threadIdx.x;
    const int wave = tid >> 6;
    const int lane = tid & 63;
    const int quad = lane >> 4;
    const int l15  = lane & 15;
    const long m0 = (long)blockIdx.x * 128;
    const long n0 = (long)blockIdx.y * 128;
    const int wm = (wave >> 1) * 64;
    const int wn = (wave & 1) * 64;
    const int s_row = tid >> 2;           // 0..63 (chunk c adds c*64)
    const int s_col = (tid & 3) * 8;      // 0,8,16,24 (u16 units)

    float4v acc[4][4];
    #pragma unroll
    for (int i = 0; i < 4; ++i)
        #pragma unroll
        for (int j = 0; j < 4; ++j)
            #pragma unroll
            for (int r = 0; r < 4; ++r) acc[i][j][r] = 0.0f;

    const u16* ga0 = A  + (m0 + s_row) * (long)K + s_col;
    const u16* ga1 = ga0 + 64 * (long)K;
    const u16* gb0 = Bt + (n0 + s_row) * (long)K + s_col;
    const u16* gb1 = gb0 + 64 * (long)K;
    u16* la = lds_a + tid * 8;            // byte offset tid*16: linear per wave
    u16* lb = lds_b + tid * 8;

    const int n_k = K >> 5;
    for (int it = 0; it < n_k; ++it) {
        const int k0 = it << 5;
        gl_lds16(ga0 + k0, la);
        gl_lds16(ga1 + k0, la + 2048);
        gl_lds16(gb0 + k0, lb);
        gl_lds16(gb1 + k0, lb + 2048);
        __syncthreads();                  // drains vmcnt(0): tile resident
        short8 af[4], bfr[4];
        #pragma unroll
        for (int mt = 0; mt < 4; ++mt)
            af[mt] = *(const short8*)(lds_a + (wm + mt * 16 + l15) * 32 + quad * 8);
        #pragma unroll
        for (int nt = 0; nt < 4; ++nt)
            bfr[nt] = *(const short8*)(lds_b + (wn + nt * 16 + l15) * 32 + quad * 8);
        #pragma unroll
        for (int mt = 0; mt < 4; ++mt)
            #pragma unroll
            for (int nt = 0; nt < 4; ++nt)
                acc[mt][nt] = __builtin_amdgcn_mfma_f32_16x16x32_bf16(af[mt], bfr[nt], acc[mt][nt], 0, 0, 0);
        __syncthreads();                  // all reads done before next overwrite
    }
    #pragma unroll
    for (int mt = 0; mt < 4; ++mt) {
        #pragma unroll
        for (int nt = 0; nt < 4; ++nt) {
            const long gr = m0 + wm + mt * 16 + quad * 4;
            const long gc = n0 + wn + nt * 16 + l15;
            #pragma unroll
            for (int r = 0; r < 4; ++r)
                C[(gr + r) * N + gc] = acc[mt][nt][r];
        }
    }
}

// ---------- 3. QKV GEMM, m97 structure, fused RMSNorm+RoPE+V-transpose ----------
// K output stored with chunk-XOR swizzle (16B chunk index ^= key&7); V output
// with 64-key-group permutation P64(k)=q4*16+kg*4+r plus chunk-XOR (^= d&7),
// so attn's linear global_load_lds staging lands a conflict-reduced LDS layout.
__global__ __launch_bounds__(256, 3) void gemm_qkv(const u16* __restrict__ A,
                                                   const u16* __restrict__ Bt,
                                                   const float* __restrict__ qw,
                                                   const float* __restrict__ kw,
                                                   const float2v* __restrict__ tab,
                                                   u16* __restrict__ Qr,
                                                   u16* __restrict__ Kr,
                                                   u16* __restrict__ Vt) {
    const int K = 2048;
    __shared__ u16 lds_a[128 * 32];
    __shared__ u16 lds_b[128 * 32];
    const int tid  = threadIdx.x;
    const int wave = tid >> 6;
    const int lane = tid & 63;
    const int quad = lane >> 4;
    const int l15  = lane & 15;
    const long m0 = (long)blockIdx.x * 128;
    const long n0 = (long)blockIdx.y * 128;
    const int wm = (wave >> 1) * 64;
    const int wn = (wave & 1) * 64;
    const int s_row = tid >> 2;
    const int s_col = (tid & 3) * 8;

    float4v acc[4][4];
    #pragma unroll
    for (int i = 0; i < 4; ++i)
        #pragma unroll
        for (int j = 0; j < 4; ++j)
            #pragma unroll
            for (int r = 0; r < 4; ++r) acc[i][j][r] = 0.0f;

    const u16* ga0 = A  + (m0 + s_row) * (long)K + s_col;
    const u16* ga1 = ga0 + 64 * (long)K;
    const u16* gb0 = Bt + (n0 + s_row) * (long)K + s_col;
    const u16* gb1 = gb0 + 64 * (long)K;
    u16* la = lds_a + tid * 8;
    u16* lb = lds_b + tid * 8;

    const int n_k = K >> 5;   // 64
    for (int it = 0; it < n_k; ++it) {
        const int k0 = it << 5;
        gl_lds16(ga0 + k0, la);
        gl_lds16(ga1 + k0, la + 2048);
        gl_lds16(gb0 + k0, lb);
        gl_lds16(gb1 + k0, lb + 2048);
        __syncthreads();
        short8 af[4], bfr[4];
        #pragma unroll
        for (int mt = 0; mt < 4; ++mt)
            af[mt] = *(const short8*)(lds_a + (wm + mt * 16 + l15) * 32 + quad * 8);
        #pragma unroll
        for (int nt = 0; nt < 4; ++nt)
            bfr[nt] = *(const short8*)(lds_b + (wn + nt * 16 + l15) * 32 + quad * 8);
        #pragma unroll
        for (int mt = 0; mt < 4; ++mt)
            #pragma unroll
            for (int nt = 0; nt < 4; ++nt)
                acc[mt][nt] = __builtin_amdgcn_mfma_f32_16x16x32_bf16(af[mt], bfr[nt], acc[mt][nt], 0, 0, 0);
        __syncthreads();
    }

    const int col0 = (int)n0 + wn;          // 64-aligned; whole wave in one zone
    if (col0 < 2560) {
        // ---- Q or K head: RMSNorm + RoPE ----
        const bool isQ = (col0 < 2048);
        const float* lw = isQ ? qw : kw;
        float wreg[4];
        #pragma unroll
        for (int nt = 0; nt < 4; ++nt) wreg[nt] = lw[nt * 16 + l15];
        const float qs = isQ ? 0.18033688011112042f : 1.0f;   // 0.125*log2(e) for Q
        const int swm = isQ ? 0 : 7;        // K rows get chunk-XOR by key&7
        u16* dst = isQ ? (Qr + ((size_t)(col0 >> 6)) * 2048 * 64)
                       : (Kr + ((size_t)((col0 - 2048) >> 6)) * 2048 * 64);
        const size_t head_stride = isQ ? ((size_t)32 * 2048 * 64) : ((size_t)8 * 2048 * 64);
        #pragma unroll
        for (int mt = 0; mt < 4; ++mt) {
            const int gr0 = (int)m0 + wm + mt * 16 + quad * 4;
            const int b = gr0 >> 11, tt0 = gr0 & 2047;
            float rms[4];
            #pragma unroll
            for (int r = 0; r < 4; ++r) {
                float s = 0.0f;
                #pragma unroll
                for (int nt = 0; nt < 4; ++nt) s += acc[mt][nt][r] * acc[mt][nt][r];
                s += __shfl_xor(s, 1);
                s += __shfl_xor(s, 2);
                s += __shfl_xor(s, 4);
                s += __shfl_xor(s, 8);
                rms[r] = rsqrtf(s * (1.0f / 64.0f) + 1e-5f);
            }
            u16* rowp = dst + (size_t)b * head_stride + (size_t)tt0 * 64;
            #pragma unroll
            for (int nt = 0; nt < 2; ++nt) {
                const int i = nt * 16 + l15;
                #pragma unroll
                for (int r = 0; r < 4; ++r) {
                    const float2v cs = tab[(tt0 + r) * 32 + i];
                    const float v1 = acc[mt][nt][r]     * rms[r] * wreg[nt];
                    const float v2 = acc[mt][nt + 2][r] * rms[r] * wreg[nt + 2];
                    const float o1 = (v1 * cs[0] - v2 * cs[1]) * qs;
                    const float o2 = (v2 * cs[0] + v1 * cs[1]) * qs;
                    const int k7 = (tt0 + r) & swm;
                    const int i1 = (((i >> 3) ^ k7) << 3) | (i & 7);
                    const int i2 = ((((i + 32) >> 3) ^ k7) << 3) | (i & 7);
                    rowp[(size_t)r * 64 + i1] = f2bf(o1);
                    rowp[(size_t)r * 64 + i2] = f2bf(o2);
                }
            }
        }
    } else {
        // ---- V head: transpose to [head][d][t'], t' = P64-swizzled within 64-key group ----
        const int kh = (col0 - 2560) >> 6;
        #pragma unroll
        for (int mt = 0; mt < 4; ++mt) {
            const int gr0 = (int)m0 + wm + mt * 16 + quad * 4;
            const int b = gr0 >> 11, tt0 = gr0 & 2047;
            const int tb = tt0 & ~63;
            const int tl = tt0 & 63;
            const int p0b = ((tl & 15) >> 2) * 16 + (tl >> 4) * 4;   // P64(tl), low2=0
            #pragma unroll
            for (int nt = 0; nt < 4; ++nt) {
                const int d = nt * 16 + l15;
                ushort4v o;
                #pragma unroll
                for (int r = 0; r < 4; ++r) o[r] = f2bf(acc[mt][nt][r]);
                const int col = tb + ((((p0b >> 3) ^ (d & 7)) << 3) | (p0b & 7));
                *(ushort4v*)(Vt + (((size_t)(b * 8 + kh)) * 64 + d) * 2048 + col) = o;
            }
        }
    }
}

// ---------- 4. flash attention: 4 waves x 2 q-frags, 64-key tiles, 1024 blocks ----------
// Occupancy fix for r5 (1 block/CU): 256 thr + 32KB LDS -> 4 blocks/CU = 16
// waves/CU = 4/SIMD. Causal grid unfolded: (64 bh, 16 qx), longest-first
// (qx = 15-y); 4-deep per-CU backfill absorbs the imbalance. 2-frag K/V reuse
// and pre-baked conflict-free layouts kept from r3/r5.
#define SOFTMAX_PACK(S, m_i, l_i, O, pf)                                    \
    {                                                                       \
        float mx = S[0][0];                                                 \
        _Pragma("unroll")                                                   \
        for (int nt = 0; nt < 4; ++nt)                                      \
            _Pragma("unroll")                                               \
            for (int r = 0; r < 4; ++r) mx = fmaxf(mx, S[nt][r]);           \
        mx = fmaxf(mx, __shfl_xor(mx, 16));                                 \
        mx = fmaxf(mx, __shfl_xor(mx, 32));                                 \
        const float mnew = fmaxf(m_i, mx);                                  \
        const float alpha = __builtin_amdgcn_exp2f(m_i - mnew);             \
        m_i = mnew;                                                         \
        float rs = 0.0f;                                                    \
        _Pragma("unroll")                                                   \
        for (int nt = 0; nt < 4; ++nt)                                      \
            _Pragma("unroll")                                               \
            for (int r = 0; r < 4; ++r) {                                   \
                const float pv = __builtin_amdgcn_exp2f(S[nt][r] - mnew);   \
                S[nt][r] = pv;                                              \
                rs += pv;                                                   \
            }                                                               \
        rs += __shfl_xor(rs, 16);                                           \
        rs += __shfl_xor(rs, 32);                                           \
        l_i = l_i * alpha + rs;                                             \
        _Pragma("unroll")                                                   \
        for (int dt = 0; dt < 4; ++dt)                                      \
            _Pragma("unroll")                                               \
            for (int r = 0; r < 4; ++r) O[dt][r] *= alpha;                  \
        _Pragma("unroll")                                                   \
        for (int nt = 0; nt < 4; ++nt) {                                    \
            union { uint32_t u[2]; short4v s; } pu;                         \
            pu.u[0] = pack_bf16x2(S[nt][0], S[nt][1]);                      \
            pu.u[1] = pack_bf16x2(S[nt][2], S[nt][3]);                      \
            pf[nt] = pu.s;                                                  \
        }                                                                   \
    }

#define WRITE_O(O, l_i, qrow)                                               \
    {                                                                       \
        const float rl = 1.0f / l_i;                                        \
        _Pragma("unroll")                                                   \
        for (int dt = 0; dt < 4; ++dt) {                                    \
            ushort4v o;                                                     \
            _Pragma("unroll")                                               \
            for (int r = 0; r < 4; ++r) o[r] = f2bf(O[dt][r] * rl);         \
            *(ushort4v*)(Ob + ((size_t)(b * 2048 + (qrow))) * 2048 +        \
                         h * 64 + dt * 16 + quad * 4) = o;                  \
        }                                                                   \
    }

__global__ __launch_bounds__(256, 4) void attn_fwd(const u16* __restrict__ Qr,
                                                   const u16* __restrict__ Kr,
                                                   const u16* __restrict__ Vt,
                                                   u16* __restrict__ Ob) {
    __shared__ u16 lds_k[2][64 * 64];    // [key][swz 16B-chunk of d]        8KB x2
    __shared__ u16 lds_v[2][64 * 64];    // [d][swz 16B-chunk of P64(key)]   8KB x2
    const int tid  = threadIdx.x;
    const int wave = tid >> 6;              // 0..3
    const int lane = tid & 63;
    const int quad = lane >> 4;
    const int l15  = lane & 15;
    const int sw7  = l15 & 7;
    const int qx = 15 - blockIdx.y;         // 15..0, longest blocks dispatched first
    const int bh = blockIdx.x;              // 0..63 (fast dim: head locality per XCD)
    const int b = bh >> 5, h = bh & 31;
    const int kh = h >> 2;
    const u16* Qh = Qr + ((size_t)(b * 32 + h))  * 2048 * 64;
    const u16* Kh = Kr + ((size_t)(b * 8 + kh))  * 2048 * 64;
    const u16* Vh = Vt + ((size_t)(b * 8 + kh))  * 64 * 2048;

    const int qrow_c0 = qx * 128 + wave * 32 + l15;
    const int qrow_c1 = qrow_c0 + 16;
    short8 qf[2][2];   // [frag][ks]
    #pragma unroll
    for (int ks = 0; ks < 2; ++ks) {
        qf[0][ks] = *(const short8*)(Qh + (size_t)qrow_c0 * 64 + ks * 32 + quad * 8);
        qf[1][ks] = *(const short8*)(Qh + (size_t)qrow_c1 * 64 + ks * 32 + quad * 8);
    }

    float m0v = -3e38f, l0v = 0.0f, m1v = -3e38f, l1v = 0.0f;
    float4v O0[4], O1[4];
    #pragma unroll
    for (int dt = 0; dt < 4; ++dt)
        #pragma unroll
        for (int r = 0; r < 4; ++r) { O0[dt][r] = 0.0f; O1[dt][r] = 0.0f; }

    // stage one 64-key tile (K 8KB + V 8KB) into buffer pb, key base k0
    const int vrow = tid >> 3;              // 0..31 (+ j*32)
    const int vchk = (tid & 7) * 8;         // u16 chunk offset within 64-key row
    auto stage = [&](int pb, int k0) {
        #pragma unroll
        for (int j = 0; j < 2; ++j)
            gl_lds16(Kh + (size_t)k0 * 64 + (j * 256 + tid) * 8,
                     &lds_k[pb][(j * 256 + tid) * 8]);
        #pragma unroll
        for (int j = 0; j < 2; ++j)
            gl_lds16(Vh + (size_t)(j * 32 + vrow) * 2048 + k0 + vchk,
                     &lds_v[pb][(j * 256 + tid) * 8]);
    };
    stage(0, 0);
    __syncthreads();

    const int n_it = 2 * qx + 2;            // 64-key tiles in this block's causal span
    for (int i = 0; i < n_it; ++i) {
        const int p = i & 1;
        const int kt0 = i << 6;

        if (i + 1 < n_it) stage(1 - p, (i + 1) << 6);

        float4v S0[4], S1[4];
        #pragma unroll
        for (int nt = 0; nt < 4; ++nt)
            #pragma unroll
            for (int r = 0; r < 4; ++r) { S0[nt][r] = 0.0f; S1[nt][r] = 0.0f; }
        __builtin_amdgcn_s_setprio(1);
        #pragma unroll
        for (int ks = 0; ks < 2; ++ks) {
            #pragma unroll
            for (int nt = 0; nt < 4; ++nt) {
                short8 kf = *(const short8*)(lds_k[p] + (nt * 16 + l15) * 64 +
                                             (((ks * 4 + quad) ^ sw7) << 3));
                S0[nt] = __builtin_amdgcn_mfma_f32_16x16x32_bf16(kf, qf[0][ks], S0[nt], 0, 0, 0);
                S1[nt] = __builtin_amdgcn_mfma_f32_16x16x32_bf16(kf, qf[1][ks], S1[nt], 0, 0, 0);
            }
        }
        __builtin_amdgcn_s_setprio(0);

        // diagonal straddles the last two 64-key tiles
        if (i >= n_it - 2) {
            #pragma unroll
            for (int nt = 0; nt < 4; ++nt) {
                const int keyb = kt0 + nt * 16 + quad * 4;
                #pragma unroll
                for (int r = 0; r < 4; ++r) {
                    if (keyb + r > qrow_c0) S0[nt][r] = -3e38f;
                    if (keyb + r > qrow_c1) S1[nt][r] = -3e38f;
                }
            }
        }

        short4v pf0[4], pf1[4];
        SOFTMAX_PACK(S0, m0v, l0v, O0, pf0);
        SOFTMAX_PACK(S1, m1v, l1v, O1, pf1);

        __builtin_amdgcn_s_setprio(1);
        #pragma unroll
        for (int nt2 = 0; nt2 < 2; ++nt2) {
            #pragma unroll
            for (int dt = 0; dt < 4; ++dt) {
                short8 vv = *(const short8*)(lds_v[p] + (dt * 16 + l15) * 64 +
                                             (((quad * 2 + nt2) ^ sw7) << 3));
                short4v vlo = __builtin_shufflevector(vv, vv, 0, 1, 2, 3);
                short4v vhi = __builtin_shufflevector(vv, vv, 4, 5, 6, 7);
                O0[dt] = __builtin_amdgcn_mfma_f32_16x16x16bf16_1k(vlo, pf0[2 * nt2],     O0[dt], 0, 0, 0);
                O0[dt] = __builtin_amdgcn_mfma_f32_16x16x16bf16_1k(vhi, pf0[2 * nt2 + 1], O0[dt], 0, 0, 0);
                O1[dt] = __builtin_amdgcn_mfma_f32_16x16x16bf16_1k(vlo, pf1[2 * nt2],     O1[dt], 0, 0, 0);
                O1[dt] = __builtin_amdgcn_mfma_f32_16x16x16bf16_1k(vhi, pf1[2 * nt2 + 1], O1[dt], 0, 0, 0);
            }
        }
        __builtin_amdgcn_s_setprio(0);

        __syncthreads();
    }
    WRITE_O(O0, l0v, qrow_c0);
    WRITE_O(O1, l1v, qrow_c1);
}

// ---------- launcher ----------
extern "C" void kernel_launch(void* const* d_in, const int* in_sizes, int n_in,
                              void* d_out, int out_size, void* d_ws, size_t ws_size,
                              hipStream_t stream) {
    (void)in_sizes; (void)n_in; (void)out_size; (void)ws_size;
    const float* x  = (const float*)d_in[0];
    const float* Wq = (const float*)d_in[1];
    const float* Wk = (const float*)d_in[2];
    const float* Wv = (const float*)d_in[3];
    const float* Wo = (const float*)d_in[4];
    const float* qw = (const float*)d_in[5];
    const float* kw = (const float*)d_in[6];
    float* out = (float*)d_out;

    char* ws = (char*)d_ws;
    size_t off = 0;
    auto alloc = [&](size_t bytes) {
        char* p = ws + off;
        off += (bytes + 255) & ~(size_t)255;
        return p;
    };
    u16* xb     = (u16*)alloc((size_t)8388608 * 2);        // x bf16       16 MB
    u16* wqkv_t = (u16*)alloc((size_t)3072 * 2048 * 2);    // [n][k]       12 MB
    u16* wo_t   = (u16*)alloc((size_t)2048 * 2048 * 2);    //               8 MB
    u16* q_r    = (u16*)alloc((size_t)2 * 32 * 2048 * 64 * 2);  // 16 MB
    u16* k_r    = (u16*)alloc((size_t)2 * 8 * 2048 * 64 * 2);   //  4 MB (chunk-swizzled)
    u16* v_r    = (u16*)alloc((size_t)2 * 8 * 64 * 2048 * 2);   //  4 MB (d-major, P64+XOR swz)
    float2v* rtab = (float2v*)alloc((size_t)2048 * 32 * 8);     // 512 KB
    u16* attnb  = xb;   // reuse: xb dead after gemm_qkv

    hipLaunchKernelGGL(prep, dim3(18688), dim3(256), 0, stream,
                       (const float4v*)x, Wq, Wk, Wv, Wo,
                       (ushort4v*)xb, wqkv_t, wo_t, rtab);
    hipLaunchKernelGGL(gemm_qkv, dim3(32, 24), dim3(256), 0, stream,
                       xb, wqkv_t, qw, kw, rtab, q_r, k_r, v_r);
    hipLaunchKernelGGL(attn_fwd, dim3(64, 16), dim3(256), 0, stream, q_r, k_r, v_r, attnb);
    hipLaunchKernelGGL(gemm_bt, dim3(32, 16), dim3(256), 0, stream,
                       attnb, wo_t, out, 4096, 2048, 2048);
}

// Round 8
// 277.934 us; speedup vs baseline: 1.4573x; 1.0366x over previous
//
#include <hip/hip_runtime.h>
#include <cstdint>
#include <cstddef>

typedef unsigned short u16;
typedef __attribute__((ext_vector_type(8))) short short8;    // 8 bf16 (4 VGPRs) MFMA A/B frag (x32)
typedef __attribute__((ext_vector_type(4))) short short4v;   // 4 bf16 (2 VGPRs) MFMA A/B frag (x16)
typedef __attribute__((ext_vector_type(4))) float float4v;   // MFMA C/D frag
typedef __attribute__((ext_vector_type(4))) unsigned short ushort4v;
typedef __attribute__((ext_vector_type(2))) float float2v;

// ---------- helpers ----------
__device__ __forceinline__ u16 f2bf(float f) {
    union { float f; uint32_t u; } x; x.f = f;
    uint32_t r = x.u + 0x7fffu + ((x.u >> 16) & 1u);   // RTNE
    return (u16)(r >> 16);
}
// pack two fp32 -> two bf16 in one dword
__device__ __forceinline__ uint32_t pack_bf16x2(float lo, float hi) {
    union { float f; uint32_t u; } a, b; a.f = lo; b.f = hi;
    return __builtin_amdgcn_perm(b.u + 0x8000u, a.u + 0x8000u, 0x07060302u);
}
// async global->LDS, 16B per lane (HW: wave-uniform base + lane*16)
__device__ __forceinline__ void gl_lds16(const u16* g, u16* l) {
    __builtin_amdgcn_global_load_lds(
        (const __attribute__((address_space(1))) void*)g,
        (__attribute__((address_space(3))) void*)l, 16, 0, 0);
}

// ---------- 1. merged prep: cast x, rope table, weight transposes ----------
__global__ __launch_bounds__(256) void prep(const float4v* __restrict__ x,
                                            const float* __restrict__ Wq,
                                            const float* __restrict__ Wk,
                                            const float* __restrict__ Wv,
                                            const float* __restrict__ Wo,
                                            ushort4v* __restrict__ xb,
                                            u16* __restrict__ wqkv_t,
                                            u16* __restrict__ wo_t,
                                            float2v* __restrict__ tab) {
    __shared__ float lds[32][33];
    const int bid = blockIdx.x;
    const int tid = threadIdx.x;
    if (bid < 8192) {
        const int i = bid * 256 + tid;
        float4v v = x[i];
        ushort4v o;
        #pragma unroll
        for (int j = 0; j < 4; ++j) o[j] = f2bf(v[j]);
        xb[i] = o;
        return;
    }
    if (bid < 8448) {
        const int idx = (bid - 8192) * 256 + tid;   // 65536
        const int t = idx >> 5;
        const int i = idx & 31;
        const float invf = exp2f(-(float)i * (19.931568569324174f / 32.0f));
        float sv, cv;
        sincosf((float)t * invf, &sv, &cv);
        float2v o; o[0] = cv; o[1] = sv;
        tab[idx] = o;
        return;
    }
    const float* src;
    int Ns, n0, k0, scol0;
    u16* dst;
    if (bid < 14592) {
        const int id = bid - 8448;
        const int bx = id % 96, by = id / 96;
        n0 = bx * 32; k0 = by * 32;
        if (n0 < 2048)      { src = Wq; Ns = 2048; scol0 = n0; }
        else if (n0 < 2560) { src = Wk; Ns = 512;  scol0 = n0 - 2048; }
        else                { src = Wv; Ns = 512;  scol0 = n0 - 2560; }
        dst = wqkv_t;
    } else {
        const int id = bid - 14592;
        const int bx = id & 63, by = id >> 6;
        n0 = bx * 32; k0 = by * 32;
        src = Wo; Ns = 2048; scol0 = n0;
        dst = wo_t;
    }
    const int row = tid >> 3;            // k local
    const int c4  = (tid & 7) * 4;       // n local
    const float4v v = *(const float4v*)(src + (size_t)(k0 + row) * Ns + scol0 + c4);
    #pragma unroll
    for (int i = 0; i < 4; ++i) lds[row][c4 + i] = v[i];
    __syncthreads();
    const int nrow = tid >> 3;           // n local
    const int k4   = (tid & 7) * 4;      // k local
    ushort4v o;
    #pragma unroll
    for (int i = 0; i < 4; ++i) o[i] = f2bf(lds[k4 + i][nrow]);
    *(ushort4v*)(dst + (size_t)(n0 + nrow) * 2048 + k0 + k4) = o;
}

// ---------- 2. output-projection GEMM, m97 structure ----------
__global__ __launch_bounds__(256, 3) void gemm_bt(const u16* __restrict__ A,
                                                  const u16* __restrict__ Bt,
                                                  float* __restrict__ C,
                                                  int M, int N, int K) {
    __shared__ u16 lds_a[128 * 32];
    __shared__ u16 lds_b[128 * 32];
    const int tid  = threadIdx.x;
    const int wave = tid >> 6;
    const int lane = tid & 63;
    const int quad = lane >> 4;
    const int l15  = lane & 15;
    const long m0 = (long)blockIdx.x * 128;
    const long n0 = (long)blockIdx.y * 128;
    const int wm = (wave >> 1) * 64;
    const int wn = (wave & 1) * 64;
    const int s_row = tid >> 2;           // 0..63 (chunk c adds c*64)
    const int s_col = (tid & 3) * 8;      // 0,8,16,24 (u16 units)

    float4v acc[4][4];
    #pragma unroll
    for (int i = 0; i < 4; ++i)
        #pragma unroll
        for (int j = 0; j < 4; ++j)
            #pragma unroll
            for (int r = 0; r < 4; ++r) acc[i][j][r] = 0.0f;

    const u16* ga0 = A  + (m0 + s_row) * (long)K + s_col;
    const u16* ga1 = ga0 + 64 * (long)K;
    const u16* gb0 = Bt + (n0 + s_row) * (long)K + s_col;
    const u16* gb1 = gb0 + 64 * (long)K;
    u16* la = lds_a + tid * 8;            // byte offset tid*16: linear per wave
    u16* lb = lds_b + tid * 8;

    const int n_k = K >> 5;
    for (int it = 0; it < n_k; ++it) {
        const int k0 = it << 5;
        gl_lds16(ga0 + k0, la);
        gl_lds16(ga1 + k0, la + 2048);
        gl_lds16(gb0 + k0, lb);
        gl_lds16(gb1 + k0, lb + 2048);
        __syncthreads();                  // drains vmcnt(0): tile resident
        short8 af[4], bfr[4];
        #pragma unroll
        for (int mt = 0; mt < 4; ++mt)
            af[mt] = *(const short8*)(lds_a + (wm + mt * 16 + l15) * 32 + quad * 8);
        #pragma unroll
        for (int nt = 0; nt < 4; ++nt)
            bfr[nt] = *(const short8*)(lds_b + (wn + nt * 16 + l15) * 32 + quad * 8);
        #pragma unroll
        for (int mt = 0; mt < 4; ++mt)
            #pragma unroll
            for (int nt = 0; nt < 4; ++nt)
                acc[mt][nt] = __builtin_amdgcn_mfma_f32_16x16x32_bf16(af[mt], bfr[nt], acc[mt][nt], 0, 0, 0);
        __syncthreads();                  // all reads done before next overwrite
    }
    #pragma unroll
    for (int mt = 0; mt < 4; ++mt) {
        #pragma unroll
        for (int nt = 0; nt < 4; ++nt) {
            const long gr = m0 + wm + mt * 16 + quad * 4;
            const long gc = n0 + wn + nt * 16 + l15;
            #pragma unroll
            for (int r = 0; r < 4; ++r)
                C[(gr + r) * N + gc] = acc[mt][nt][r];
        }
    }
}

// ---------- 3. QKV GEMM, m97 structure, fused RMSNorm+RoPE+V-transpose ----------
// K output stored with chunk-XOR swizzle (16B chunk index ^= key&7); V output
// with 64-key-group permutation P64(k)=q4*16+kg*4+r plus chunk-XOR (^= d&7),
// so attn's linear global_load_lds staging lands a conflict-reduced LDS layout.
__global__ __launch_bounds__(256, 3) void gemm_qkv(const u16* __restrict__ A,
                                                   const u16* __restrict__ Bt,
                                                   const float* __restrict__ qw,
                                                   const float* __restrict__ kw,
                                                   const float2v* __restrict__ tab,
                                                   u16* __restrict__ Qr,
                                                   u16* __restrict__ Kr,
                                                   u16* __restrict__ Vt) {
    const int K = 2048;
    __shared__ u16 lds_a[128 * 32];
    __shared__ u16 lds_b[128 * 32];
    const int tid  = threadIdx.x;
    const int wave = tid >> 6;
    const int lane = tid & 63;
    const int quad = lane >> 4;
    const int l15  = lane & 15;
    const long m0 = (long)blockIdx.x * 128;
    const long n0 = (long)blockIdx.y * 128;
    const int wm = (wave >> 1) * 64;
    const int wn = (wave & 1) * 64;
    const int s_row = tid >> 2;
    const int s_col = (tid & 3) * 8;

    float4v acc[4][4];
    #pragma unroll
    for (int i = 0; i < 4; ++i)
        #pragma unroll
        for (int j = 0; j < 4; ++j)
            #pragma unroll
            for (int r = 0; r < 4; ++r) acc[i][j][r] = 0.0f;

    const u16* ga0 = A  + (m0 + s_row) * (long)K + s_col;
    const u16* ga1 = ga0 + 64 * (long)K;
    const u16* gb0 = Bt + (n0 + s_row) * (long)K + s_col;
    const u16* gb1 = gb0 + 64 * (long)K;
    u16* la = lds_a + tid * 8;
    u16* lb = lds_b + tid * 8;

    const int n_k = K >> 5;   // 64
    for (int it = 0; it < n_k; ++it) {
        const int k0 = it << 5;
        gl_lds16(ga0 + k0, la);
        gl_lds16(ga1 + k0, la + 2048);
        gl_lds16(gb0 + k0, lb);
        gl_lds16(gb1 + k0, lb + 2048);
        __syncthreads();
        short8 af[4], bfr[4];
        #pragma unroll
        for (int mt = 0; mt < 4; ++mt)
            af[mt] = *(const short8*)(lds_a + (wm + mt * 16 + l15) * 32 + quad * 8);
        #pragma unroll
        for (int nt = 0; nt < 4; ++nt)
            bfr[nt] = *(const short8*)(lds_b + (wn + nt * 16 + l15) * 32 + quad * 8);
        #pragma unroll
        for (int mt = 0; mt < 4; ++mt)
            #pragma unroll
            for (int nt = 0; nt < 4; ++nt)
                acc[mt][nt] = __builtin_amdgcn_mfma_f32_16x16x32_bf16(af[mt], bfr[nt], acc[mt][nt], 0, 0, 0);
        __syncthreads();
    }

    const int col0 = (int)n0 + wn;          // 64-aligned; whole wave in one zone
    if (col0 < 2560) {
        // ---- Q or K head: RMSNorm + RoPE ----
        const bool isQ = (col0 < 2048);
        const float* lw = isQ ? qw : kw;
        float wreg[4];
        #pragma unroll
        for (int nt = 0; nt < 4; ++nt) wreg[nt] = lw[nt * 16 + l15];
        const float qs = isQ ? 0.18033688011112042f : 1.0f;   // 0.125*log2(e) for Q
        const int swm = isQ ? 0 : 7;        // K rows get chunk-XOR by key&7
        u16* dst = isQ ? (Qr + ((size_t)(col0 >> 6)) * 2048 * 64)
                       : (Kr + ((size_t)((col0 - 2048) >> 6)) * 2048 * 64);
        const size_t head_stride = isQ ? ((size_t)32 * 2048 * 64) : ((size_t)8 * 2048 * 64);
        #pragma unroll
        for (int mt = 0; mt < 4; ++mt) {
            const int gr0 = (int)m0 + wm + mt * 16 + quad * 4;
            const int b = gr0 >> 11, tt0 = gr0 & 2047;
            float rms[4];
            #pragma unroll
            for (int r = 0; r < 4; ++r) {
                float s = 0.0f;
                #pragma unroll
                for (int nt = 0; nt < 4; ++nt) s += acc[mt][nt][r] * acc[mt][nt][r];
                s += __shfl_xor(s, 1);
                s += __shfl_xor(s, 2);
                s += __shfl_xor(s, 4);
                s += __shfl_xor(s, 8);
                rms[r] = rsqrtf(s * (1.0f / 64.0f) + 1e-5f);
            }
            u16* rowp = dst + (size_t)b * head_stride + (size_t)tt0 * 64;
            #pragma unroll
            for (int nt = 0; nt < 2; ++nt) {
                const int i = nt * 16 + l15;
                #pragma unroll
                for (int r = 0; r < 4; ++r) {
                    const float2v cs = tab[(tt0 + r) * 32 + i];
                    const float v1 = acc[mt][nt][r]     * rms[r] * wreg[nt];
                    const float v2 = acc[mt][nt + 2][r] * rms[r] * wreg[nt + 2];
                    const float o1 = (v1 * cs[0] - v2 * cs[1]) * qs;
                    const float o2 = (v2 * cs[0] + v1 * cs[1]) * qs;
                    const int k7 = (tt0 + r) & swm;
                    const int i1 = (((i >> 3) ^ k7) << 3) | (i & 7);
                    const int i2 = ((((i + 32) >> 3) ^ k7) << 3) | (i & 7);
                    rowp[(size_t)r * 64 + i1] = f2bf(o1);
                    rowp[(size_t)r * 64 + i2] = f2bf(o2);
                }
            }
        }
    } else {
        // ---- V head: transpose to [head][d][t'], t' = P64-swizzled within 64-key group ----
        const int kh = (col0 - 2560) >> 6;
        #pragma unroll
        for (int mt = 0; mt < 4; ++mt) {
            const int gr0 = (int)m0 + wm + mt * 16 + quad * 4;
            const int b = gr0 >> 11, tt0 = gr0 & 2047;
            const int tb = tt0 & ~63;
            const int tl = tt0 & 63;
            const int p0b = ((tl & 15) >> 2) * 16 + (tl >> 4) * 4;   // P64(tl), low2=0
            #pragma unroll
            for (int nt = 0; nt < 4; ++nt) {
                const int d = nt * 16 + l15;
                ushort4v o;
                #pragma unroll
                for (int r = 0; r < 4; ++r) o[r] = f2bf(acc[mt][nt][r]);
                const int col = tb + ((((p0b >> 3) ^ (d & 7)) << 3) | (p0b & 7));
                *(ushort4v*)(Vt + (((size_t)(b * 8 + kh)) * 64 + d) * 2048 + col) = o;
            }
        }
    }
}

// ---------- 4. flash attention: fixed-max softmax (no running max/rescale) ----------
// r7 structure kept (4 waves x 2 q-frags, 64-key tiles, 1024 blocks, gl_lds,
// pre-baked conflict-free layouts). Softmax max-tracking ELIMINATED: Q rows are
// RMS-normed (norm 8) * 0.125*log2e, K rows norm 8 => |S| <= 64*0.125*log2e =
// 11.54 (hard Cauchy-Schwarz bound, log2 domain). Fixed M0=12: P = exp2(S-12)
// in (0, 0.73], diagonal P >= 2^-0.46 so l in [0.73, 2048] -- no overflow, no
// rescale, l is a pure sum (per-lane partial, one final shfl reduce).
#define SOFTMAX_PACK(S, l_i, pf)                                            \
    {                                                                       \
        float rs = 0.0f;                                                    \
        _Pragma("unroll")                                                   \
        for (int nt = 0; nt < 4; ++nt)                                      \
            _Pragma("unroll")                                               \
            for (int r = 0; r < 4; ++r) {                                   \
                const float pv = __builtin_amdgcn_exp2f(S[nt][r] - 12.0f);  \
                S[nt][r] = pv;                                              \
                rs += pv;                                                   \
            }                                                               \
        l_i += rs;                                                          \
        _Pragma("unroll")                                                   \
        for (int nt = 0; nt < 4; ++nt) {                                    \
            union { uint32_t u[2]; short4v s; } pu;                         \
            pu.u[0] = pack_bf16x2(S[nt][0], S[nt][1]);                      \
            pu.u[1] = pack_bf16x2(S[nt][2], S[nt][3]);                      \
            pf[nt] = pu.s;                                                  \
        }                                                                   \
    }

#define WRITE_O(O, l_i, qrow)                                               \
    {                                                                       \
        float lt = l_i;                                                     \
        lt += __shfl_xor(lt, 16);                                           \
        lt += __shfl_xor(lt, 32);                                           \
        const float rl = 1.0f / lt;                                         \
        _Pragma("unroll")                                                   \
        for (int dt = 0; dt < 4; ++dt) {                                    \
            ushort4v o;                                                     \
            _Pragma("unroll")                                               \
            for (int r = 0; r < 4; ++r) o[r] = f2bf(O[dt][r] * rl);         \
            *(ushort4v*)(Ob + ((size_t)(b * 2048 + (qrow))) * 2048 +        \
                         h * 64 + dt * 16 + quad * 4) = o;                  \
        }                                                                   \
    }

__global__ __launch_bounds__(256, 4) void attn_fwd(const u16* __restrict__ Qr,
                                                   const u16* __restrict__ Kr,
                                                   const u16* __restrict__ Vt,
                                                   u16* __restrict__ Ob) {
    __shared__ u16 lds_k[2][64 * 64];    // [key][swz 16B-chunk of d]        8KB x2
    __shared__ u16 lds_v[2][64 * 64];    // [d][swz 16B-chunk of P64(key)]   8KB x2
    const int tid  = threadIdx.x;
    const int wave = tid >> 6;              // 0..3
    const int lane = tid & 63;
    const int quad = lane >> 4;
    const int l15  = lane & 15;
    const int sw7  = l15 & 7;
    const int qx = 15 - blockIdx.y;         // 15..0, longest blocks dispatched first
    const int bh = blockIdx.x;              // 0..63 (fast dim: head locality per XCD)
    const int b = bh >> 5, h = bh & 31;
    const int kh = h >> 2;
    const u16* Qh = Qr + ((size_t)(b * 32 + h))  * 2048 * 64;
    const u16* Kh = Kr + ((size_t)(b * 8 + kh))  * 2048 * 64;
    const u16* Vh = Vt + ((size_t)(b * 8 + kh))  * 64 * 2048;

    const int qrow_c0 = qx * 128 + wave * 32 + l15;
    const int qrow_c1 = qrow_c0 + 16;
    short8 qf[2][2];   // [frag][ks]
    #pragma unroll
    for (int ks = 0; ks < 2; ++ks) {
        qf[0][ks] = *(const short8*)(Qh + (size_t)qrow_c0 * 64 + ks * 32 + quad * 8);
        qf[1][ks] = *(const short8*)(Qh + (size_t)qrow_c1 * 64 + ks * 32 + quad * 8);
    }

    float l0v = 0.0f, l1v = 0.0f;
    float4v O0[4], O1[4];
    #pragma unroll
    for (int dt = 0; dt < 4; ++dt)
        #pragma unroll
        for (int r = 0; r < 4; ++r) { O0[dt][r] = 0.0f; O1[dt][r] = 0.0f; }

    // stage one 64-key tile (K 8KB + V 8KB) into buffer pb, key base k0
    const int vrow = tid >> 3;              // 0..31 (+ j*32)
    const int vchk = (tid & 7) * 8;         // u16 chunk offset within 64-key row
    auto stage = [&](int pb, int k0) {
        #pragma unroll
        for (int j = 0; j < 2; ++j)
            gl_lds16(Kh + (size_t)k0 * 64 + (j * 256 + tid) * 8,
                     &lds_k[pb][(j * 256 + tid) * 8]);
        #pragma unroll
        for (int j = 0; j < 2; ++j)
            gl_lds16(Vh + (size_t)(j * 32 + vrow) * 2048 + k0 + vchk,
                     &lds_v[pb][(j * 256 + tid) * 8]);
    };
    stage(0, 0);
    __syncthreads();

    const int n_it = 2 * qx + 2;            // 64-key tiles in this block's causal span
    for (int i = 0; i < n_it; ++i) {
        const int p = i & 1;
        const int kt0 = i << 6;

        if (i + 1 < n_it) stage(1 - p, (i + 1) << 6);

        float4v S0[4], S1[4];
        #pragma unroll
        for (int nt = 0; nt < 4; ++nt)
            #pragma unroll
            for (int r = 0; r < 4; ++r) { S0[nt][r] = 0.0f; S1[nt][r] = 0.0f; }
        __builtin_amdgcn_s_setprio(1);
        #pragma unroll
        for (int ks = 0; ks < 2; ++ks) {
            #pragma unroll
            for (int nt = 0; nt < 4; ++nt) {
                short8 kf = *(const short8*)(lds_k[p] + (nt * 16 + l15) * 64 +
                                             (((ks * 4 + quad) ^ sw7) << 3));
                S0[nt] = __builtin_amdgcn_mfma_f32_16x16x32_bf16(kf, qf[0][ks], S0[nt], 0, 0, 0);
                S1[nt] = __builtin_amdgcn_mfma_f32_16x16x32_bf16(kf, qf[1][ks], S1[nt], 0, 0, 0);
            }
        }
        __builtin_amdgcn_s_setprio(0);

        // diagonal straddles the last two 64-key tiles
        if (i >= n_it - 2) {
            #pragma unroll
            for (int nt = 0; nt < 4; ++nt) {
                const int keyb = kt0 + nt * 16 + quad * 4;
                #pragma unroll
                for (int r = 0; r < 4; ++r) {
                    if (keyb + r > qrow_c0) S0[nt][r] = -3e38f;
                    if (keyb + r > qrow_c1) S1[nt][r] = -3e38f;
                }
            }
        }

        short4v pf0[4], pf1[4];
        SOFTMAX_PACK(S0, l0v, pf0);
        SOFTMAX_PACK(S1, l1v, pf1);

        __builtin_amdgcn_s_setprio(1);
        #pragma unroll
        for (int nt2 = 0; nt2 < 2; ++nt2) {
            #pragma unroll
            for (int dt = 0; dt < 4; ++dt) {
                short8 vv = *(const short8*)(lds_v[p] + (dt * 16 + l15) * 64 +
                                             (((quad * 2 + nt2) ^ sw7) << 3));
                short4v vlo = __builtin_shufflevector(vv, vv, 0, 1, 2, 3);
                short4v vhi = __builtin_shufflevector(vv, vv, 4, 5, 6, 7);
                O0[dt] = __builtin_amdgcn_mfma_f32_16x16x16bf16_1k(vlo, pf0[2 * nt2],     O0[dt], 0, 0, 0);
                O0[dt] = __builtin_amdgcn_mfma_f32_16x16x16bf16_1k(vhi, pf0[2 * nt2 + 1], O0[dt], 0, 0, 0);
                O1[dt] = __builtin_amdgcn_mfma_f32_16x16x16bf16_1k(vlo, pf1[2 * nt2],     O1[dt], 0, 0, 0);
                O1[dt] = __builtin_amdgcn_mfma_f32_16x16x16bf16_1k(vhi, pf1[2 * nt2 + 1], O1[dt], 0, 0, 0);
            }
        }
        __builtin_amdgcn_s_setprio(0);

        __syncthreads();
    }
    WRITE_O(O0, l0v, qrow_c0);
    WRITE_O(O1, l1v, qrow_c1);
}

// ---------- launcher ----------
extern "C" void kernel_launch(void* const* d_in, const int* in_sizes, int n_in,
                              void* d_out, int out_size, void* d_ws, size_t ws_size,
                              hipStream_t stream) {
    (void)in_sizes; (void)n_in; (void)out_size; (void)ws_size;
    const float* x  = (const float*)d_in[0];
    const float* Wq = (const float*)d_in[1];
    const float* Wk = (const float*)d_in[2];
    const float* Wv = (const float*)d_in[3];
    const float* Wo = (const float*)d_in[4];
    const float* qw = (const float*)d_in[5];
    const float* kw = (const float*)d_in[6];
    float* out = (float*)d_out;

    char* ws = (char*)d_ws;
    size_t off = 0;
    auto alloc = [&](size_t bytes) {
        char* p = ws + off;
        off += (bytes + 255) & ~(size_t)255;
        return p;
    };
    u16* xb     = (u16*)alloc((size_t)8388608 * 2);        // x bf16       16 MB
    u16* wqkv_t = (u16*)alloc((size_t)3072 * 2048 * 2);    // [n][k]       12 MB
    u16* wo_t   = (u16*)alloc((size_t)2048 * 2048 * 2);    //               8 MB
    u16* q_r    = (u16*)alloc((size_t)2 * 32 * 2048 * 64 * 2);  // 16 MB
    u16* k_r    = (u16*)alloc((size_t)2 * 8 * 2048 * 64 * 2);   //  4 MB (chunk-swizzled)
    u16* v_r    = (u16*)alloc((size_t)2 * 8 * 64 * 2048 * 2);   //  4 MB (d-major, P64+XOR swz)
    float2v* rtab = (float2v*)alloc((size_t)2048 * 32 * 8);     // 512 KB
    u16* attnb  = xb;   // reuse: xb dead after gemm_qkv

    hipLaunchKernelGGL(prep, dim3(18688), dim3(256), 0, stream,
                       (const float4v*)x, Wq, Wk, Wv, Wo,
                       (ushort4v*)xb, wqkv_t, wo_t, rtab);
    hipLaunchKernelGGL(gemm_qkv, dim3(32, 24), dim3(256), 0, stream,
                       xb, wqkv_t, qw, kw, rtab, q_r, k_r, v_r);
    hipLaunchKernelGGL(attn_fwd, dim3(64, 16), dim3(256), 0, stream, q_r, k_r, v_r, attnb);
    hipLaunchKernelGGL(gemm_bt, dim3(32, 16), dim3(256), 0, stream,
                       attnb, wo_t, out, 4096, 2048, 2048);
}